// Round 3
// baseline (6298.370 us; speedup 1.0000x reference)
//
#include <hip/hip_runtime.h>
#include <math.h>

#define N_NODES 30000
#define N_EDGES 480000
#define N_GRAPHS 16
#define HID 128
#define HEADS 8
#define HEAD_DIM 16
#define NODE_IN 64
#define EDGE_IN 32
#define COND 8
#define NODE_OUT 64
#define NLAYERS 4
#define EF (N_EDGES + N_NODES) /* 510000 */
#define LN_EPS 1e-5f

#define ETILE 16        /* edges per att/enc block */
#define EA_STRIDE 132   /* sh_ea row stride (floats); 4-float aligned */

__device__ __forceinline__ float gelu_f(float x) {
    return 0.5f * x * (1.0f + erff(x * 0.70710678118654752440f));
}

__device__ __forceinline__ void atomicMaxF(float* addr, float val) {
    if (val >= 0.0f) {
        atomicMax((int*)addr, __float_as_int(val));
    } else {
        atomicMin((unsigned int*)addr, __float_as_uint(val));
    }
}

// ---------- generic zero ----------
__global__ void zero_kernel(float* __restrict__ p, long n) {
    long i = (long)blockIdx.x * blockDim.x + threadIdx.x;
    long stride = (long)gridDim.x * blockDim.x;
    for (; i < n; i += stride) p[i] = 0.0f;
}

// ---------- time MLP: t[16] -> t_emb[16,128] ----------
__global__ void time_mlp_kernel(const float* __restrict__ t,
                                const float* __restrict__ tW1, const float* __restrict__ tb1,
                                const float* __restrict__ tW2, const float* __restrict__ tb2,
                                float* __restrict__ t_emb) {
    __shared__ float hsh[HID];
    int b = blockIdx.x, j = threadIdx.x;
    float tv = t[b];
    hsh[j] = gelu_f(tv * tW1[j] + tb1[j]);
    __syncthreads();
    float acc = tb2[j];
    for (int k = 0; k < HID; ++k) acc += hsh[k] * tW2[k * HID + j];
    t_emb[b * HID + j] = acc;
}

// ---------- concat x(64) + conditions[batch](8) -> xc[N,72] ----------
__global__ void concat_kernel(const float* __restrict__ x, const float* __restrict__ cond,
                              const int* __restrict__ batch, float* __restrict__ xc) {
    int idx = blockIdx.x * blockDim.x + threadIdx.x;
    if (idx >= N_NODES * 72) return;
    int n = idx / 72, c = idx % 72;
    xc[idx] = (c < NODE_IN) ? x[n * NODE_IN + c] : cond[batch[n] * COND + (c - NODE_IN)];
}

// ---------- generic GEMM: C[M,NCOL] = A[M,K] @ B[K,NCOL] + bias ----------
// K must be a multiple of 4. Inner loop: float4 broadcast LDS reads.
template <int NCOL, int R>
__global__ void gemm_kernel(const float* __restrict__ A, const float* __restrict__ B,
                            const float* __restrict__ bias, float* __restrict__ C,
                            int M, int K) {
    __shared__ __align__(16) float sh[R * HID];
    int j = threadIdx.x;
    int row0 = blockIdx.x * R;
    int total = R * K;
    for (int i = j; i < total; i += NCOL) {
        int r = i / K, k = i - r * K;
        int row = row0 + r;
        sh[r * K + k] = (row < M) ? A[(long)row * K + k] : 0.0f;
    }
    __syncthreads();
    float acc[R];
    float bv = bias ? bias[j] : 0.0f;
#pragma unroll
    for (int r = 0; r < R; ++r) acc[r] = bv;
    int KB = K >> 2;
    for (int kb = 0; kb < KB; ++kb) {
        float w0 = B[(kb * 4 + 0) * NCOL + j];
        float w1 = B[(kb * 4 + 1) * NCOL + j];
        float w2 = B[(kb * 4 + 2) * NCOL + j];
        float w3 = B[(kb * 4 + 3) * NCOL + j];
#pragma unroll
        for (int r = 0; r < R; ++r) {
            float4 a = *(const float4*)&sh[r * K + kb * 4];
            acc[r] += a.x * w0 + a.y * w1 + a.z * w2 + a.w * w3;
        }
    }
#pragma unroll
    for (int r = 0; r < R; ++r) {
        int row = row0 + r;
        if (row < M) C[(long)row * NCOL + j] = acc[r];
    }
}

// ---------- in-place LayerNorm + GELU (+ optional t_emb[batch[row]]) ----------
__global__ void ln_gelu_kernel(float* __restrict__ X, const float* __restrict__ g,
                               const float* __restrict__ bta,
                               const float* __restrict__ t_emb, const int* __restrict__ batch) {
    int row = blockIdx.x, j = threadIdx.x;
    __shared__ float red[HID];
    float v = X[(long)row * HID + j];
    red[j] = v;
    __syncthreads();
    for (int s = 64; s > 0; s >>= 1) { if (j < s) red[j] += red[j + s]; __syncthreads(); }
    float mean = red[0] * (1.0f / HID);
    __syncthreads();
    float d = v - mean;
    red[j] = d * d;
    __syncthreads();
    for (int s = 64; s > 0; s >>= 1) { if (j < s) red[j] += red[j + s]; __syncthreads(); }
    float var = red[0] * (1.0f / HID);
    float y = gelu_f(d * rsqrtf(var + LN_EPS) * g[j] + bta[j]);
    if (t_emb) y += t_emb[batch[row] * HID + j];
    X[(long)row * HID + j] = y;
}

// ---------- weight prep: k-tiled transposes ----------
// eWT4[kb][j][kk] = eW[kb*4+kk][j]   (8*128*4 floats)
// BT4 [l][kb][c][kk] = cWe[l][kb*4+kk][c]  (4*32*128*4 floats)
__global__ void prep_weights_kernel(const float* __restrict__ eW, const float* __restrict__ cWe,
                                    float* __restrict__ eWT4, float* __restrict__ BT4) {
    int idx = blockIdx.x * blockDim.x + threadIdx.x;
    if (idx < 8 * HID * 4) {
        int kb = idx >> 9, rem = idx & 511, j = rem >> 2, kk = rem & 3;
        eWT4[idx] = eW[(kb * 4 + kk) * HID + j];
    }
    if (idx < NLAYERS * 32 * HID * 4) {
        int l = idx >> 14, rem = idx & 16383;
        int kb = rem >> 9, r2 = rem & 511, c = r2 >> 2, kk = r2 & 3;
        BT4[idx] = cWe[l * HID * HID + (kb * 4 + kk) * HID + c];
    }
}

// ---------- fused: wave-parallel edge-encode + segment-sum into loop_sum/cnt ----------
// 256 threads, 16 edges/block. Wave w encodes rows w*4..w*4+3; lane holds cols (lane, lane+64).
__global__ __launch_bounds__(256, 4) void edge_enc_loop3_kernel(
        const float* __restrict__ edge_attr, const float* __restrict__ eWT4,
        const float* __restrict__ eb, const float* __restrict__ eg, const float* __restrict__ ebe,
        const int* __restrict__ ei_dst,
        float* __restrict__ loop_sum, float* __restrict__ cnt) {
    __shared__ __align__(16) float sattr[ETILE * EDGE_IN];
    __shared__ int sdst[ETILE];
    int t = threadIdx.x;
    long e0 = (long)blockIdx.x * ETILE;
    if (t < ETILE * EDGE_IN / 4)
        ((float4*)sattr)[t] = ((const float4*)(edge_attr + e0 * EDGE_IN))[t];
    if (t < ETILE) sdst[t] = ei_dst[e0 + t];
    __syncthreads();
    int lane = t & 63, w = t >> 6;
    int j1 = lane, j2 = lane + 64;
    int r0 = w * 4;
    float ebv0 = eb[j1], ebv1 = eb[j2];
    float egv0 = eg[j1], egv1 = eg[j2];
    float bev0 = ebe[j1], bev1 = ebe[j2];
    const float4* EW4 = (const float4*)eWT4;
    float v0[4], v1[4];
#pragma unroll
    for (int q = 0; q < 4; ++q) { v0[q] = ebv0; v1[q] = ebv1; }
#pragma unroll
    for (int kb = 0; kb < 8; ++kb) {
        float4 w0 = EW4[kb * HID + j1];
        float4 w1 = EW4[kb * HID + j2];
#pragma unroll
        for (int q = 0; q < 4; ++q) {
            float4 av = *(const float4*)&sattr[(r0 + q) * EDGE_IN + kb * 4];
            v0[q] += av.x * w0.x + av.y * w0.y + av.z * w0.z + av.w * w0.w;
            v1[q] += av.x * w1.x + av.y * w1.y + av.z * w1.z + av.w * w1.w;
        }
    }
#pragma unroll
    for (int q = 0; q < 4; ++q) {
        float s1 = v0[q] + v1[q];
        float s2 = v0[q] * v0[q] + v1[q] * v1[q];
#pragma unroll
        for (int m = 1; m < 64; m <<= 1) {
            s1 += __shfl_xor(s1, m);
            s2 += __shfl_xor(s2, m);
        }
        float mean = s1 * (1.0f / 128.0f);
        float var = s2 * (1.0f / 128.0f) - mean * mean;
        float rs = rsqrtf(var + LN_EPS);
        float y0 = gelu_f((v0[q] - mean) * rs * egv0 + bev0);
        float y1 = gelu_f((v1[q] - mean) * rs * egv1 + bev1);
        int d = sdst[r0 + q];
        atomicAdd(&loop_sum[(long)d * HID + j1], y0);
        atomicAdd(&loop_sum[(long)d * HID + j2], y1);
        if (lane == 0) atomicAdd(&cnt[d], 1.0f);
    }
}

__global__ void loop_div_kernel(float* __restrict__ loop_attr, const float* __restrict__ cnt) {
    int idx = blockIdx.x * blockDim.x + threadIdx.x;
    if (idx >= N_NODES * HID) return;
    int n = idx >> 7;
    loop_attr[idx] = loop_attr[idx] / fmaxf(cnt[n], 1.0f);
}

// ---------- init mx=-inf, den=0 ----------
__global__ void init_mx_den_kernel(float* __restrict__ mx, float* __restrict__ den) {
    int idx = blockIdx.x * blockDim.x + threadIdx.x;
    if (idx >= N_NODES * HEADS) return;
    mx[idx] = -INFINITY;
    den[idx] = 0.0f;
}

// ---------- tiled fused: edge-encode + em GEMM + leakyrelu + logit + atomicMax ----------
// Block: 256 threads, 16 edges (ETILE).
// Encode: wave w rows w*4..w*4+3; lane holds cols (lane, lane+64); LN via shfl_xor.
// GEMM:   thread t owns column j=t&127 for 8 rows (half p=t>>7); acc[8].
//         All lanes of a wave read the same sh_ea 16B -> broadcast, conflict-free.
//         B loads (BT4) are per-thread coalesced float4 with 1-deep prefetch.
template <bool SELFLOOP>
__global__ __launch_bounds__(256, 4) void att_logit4_kernel(
        const float* __restrict__ edge_attr,
        const float* __restrict__ eWT4,
        const float* __restrict__ eb, const float* __restrict__ eg, const float* __restrict__ ebe,
        const float* __restrict__ loop_attr,
        const float* __restrict__ BT4_l,   /* [32][128][4] this layer */
        const float* __restrict__ catt_l,  /* [128] */
        const float* __restrict__ xl, const float* __restrict__ xr,
        const int* __restrict__ ei_src, const int* __restrict__ ei_dst,
        float* __restrict__ logit, float* __restrict__ mx) {
    __shared__ __align__(16) float sh_ea[ETILE * EA_STRIDE];
    __shared__ __align__(16) float sattr[ETILE * EDGE_IN];
    __shared__ int ssrc[ETILE], sdst[ETILE];
    int t = threadIdx.x;
    long e0 = (long)blockIdx.x * ETILE + (SELFLOOP ? N_EDGES : 0);

    // ---- phase 0: stage inputs ----
    if (!SELFLOOP) {
        if (t < ETILE * EDGE_IN / 4)
            ((float4*)sattr)[t] = ((const float4*)(edge_attr + e0 * EDGE_IN))[t];
        if (t < ETILE) ssrc[t] = ei_src[e0 + t];
        else if (t < 2 * ETILE) sdst[t - ETILE] = ei_dst[e0 + (t - ETILE)];
    } else {
        int n0 = (int)(e0 - N_EDGES);
        for (int idx = t; idx < ETILE * (HID / 4); idx += 256) {
            int r = idx >> 5, c4 = idx & 31;
            int n = n0 + r;
            float4 v = make_float4(0.f, 0.f, 0.f, 0.f);
            if (n < N_NODES) v = *(const float4*)&loop_attr[(long)n * HID + c4 * 4];
            *(float4*)&sh_ea[r * EA_STRIDE + c4 * 4] = v;
        }
        if (t < ETILE) { int n = n0 + t; ssrc[t] = sdst[t] = (n < N_NODES) ? n : 0; }
    }
    __syncthreads();

    // ---- phase 1: encode (real edges only) ----
    if (!SELFLOOP) {
        int lane = t & 63, w = t >> 6;
        int j1 = lane, j2 = lane + 64;
        int r0 = w * 4;
        float ebv0 = eb[j1], ebv1 = eb[j2];
        float egv0 = eg[j1], egv1 = eg[j2];
        float bev0 = ebe[j1], bev1 = ebe[j2];
        const float4* EW4 = (const float4*)eWT4;
        float v0[4], v1[4];
#pragma unroll
        for (int q = 0; q < 4; ++q) { v0[q] = ebv0; v1[q] = ebv1; }
#pragma unroll
        for (int kb = 0; kb < 8; ++kb) {
            float4 w0 = EW4[kb * HID + j1];
            float4 w1 = EW4[kb * HID + j2];
#pragma unroll
            for (int q = 0; q < 4; ++q) {
                float4 av = *(const float4*)&sattr[(r0 + q) * EDGE_IN + kb * 4];
                v0[q] += av.x * w0.x + av.y * w0.y + av.z * w0.z + av.w * w0.w;
                v1[q] += av.x * w1.x + av.y * w1.y + av.z * w1.z + av.w * w1.w;
            }
        }
#pragma unroll
        for (int q = 0; q < 4; ++q) {
            float s1 = v0[q] + v1[q];
            float s2 = v0[q] * v0[q] + v1[q] * v1[q];
#pragma unroll
            for (int m = 1; m < 64; m <<= 1) {
                s1 += __shfl_xor(s1, m);
                s2 += __shfl_xor(s2, m);
            }
            float mean = s1 * (1.0f / 128.0f);
            float var = s2 * (1.0f / 128.0f) - mean * mean;
            float rs = rsqrtf(var + LN_EPS);
            sh_ea[(r0 + q) * EA_STRIDE + j1] = gelu_f((v0[q] - mean) * rs * egv0 + bev0);
            sh_ea[(r0 + q) * EA_STRIDE + j2] = gelu_f((v1[q] - mean) * rs * egv1 + bev1);
        }
    }
    __syncthreads();

    // ---- phase 2: em GEMM, 1 col x 8 rows per thread ----
    int j = t & 127;
    int p = t >> 7;            // row half: rows p*8 .. p*8+7
    int rbase = p * 8;
    float acc[8];
#pragma unroll
    for (int i = 0; i < 8; ++i) acc[i] = 0.0f;
    const float4* B4 = (const float4*)BT4_l;
    float4 b = B4[j];  // kb = 0
    for (int kb = 0; kb < 32; ++kb) {
        float4 bn = (kb < 31) ? B4[(kb + 1) * HID + j] : b;
#pragma unroll
        for (int i = 0; i < 8; ++i) {
            float4 a = *(const float4*)&sh_ea[(rbase + i) * EA_STRIDE + kb * 4];
            acc[i] += a.x * b.x + a.y * b.y + a.z * b.z + a.w * b.w;
        }
        b = bn;
    }

    // ---- phase 3: logit + 16-lane head reduce + atomic max ----
    float cj = catt_l[j];
    int head = j >> 4;
#pragma unroll
    for (int i = 0; i < 8; ++i) {
        int r = rbase + i;
        long e = e0 + r;
        int s = ssrc[r], d = sdst[r];
        float m = xl[(long)s * HID + j] + xr[(long)d * HID + j] + acc[i];
        m = (m > 0.0f) ? m : 0.2f * m;
        float pj = m * cj;
        pj += __shfl_xor(pj, 1);
        pj += __shfl_xor(pj, 2);
        pj += __shfl_xor(pj, 4);
        pj += __shfl_xor(pj, 8);
        if ((j & 15) == 0) {
            logit[e * HEADS + head] = pj;
            atomicMaxF(&mx[(long)d * HEADS + head], pj);
        }
    }
}

// ---------- exp(logit-mx), accumulate denominator ----------
__global__ void softmax_norm_kernel(const int* __restrict__ ei_dst, const float* __restrict__ mx,
                                    float* __restrict__ logit, float* __restrict__ den) {
    long idx = (long)blockIdx.x * blockDim.x + threadIdx.x;
    if (idx >= (long)EF * HEADS) return;
    long e = idx >> 3;
    int hh = (int)(idx & 7);
    int d = (e < N_EDGES) ? ei_dst[e] : (int)(e - N_EDGES);
    float ex = expf(logit[idx] - mx[(long)d * HEADS + hh]);
    logit[idx] = ex;
    atomicAdd(&den[(long)d * HEADS + hh], ex);
}

// ---------- alpha-weighted aggregation ----------
__global__ void aggregate_kernel(const float* __restrict__ logit, const float* __restrict__ den,
                                 const float* __restrict__ xl,
                                 const int* __restrict__ ei_src, const int* __restrict__ ei_dst,
                                 float* __restrict__ aggout) {
    long idx = (long)blockIdx.x * blockDim.x + threadIdx.x;
    if (idx >= (long)EF * HID) return;
    long e = idx >> 7;
    int j = (int)(idx & 127);
    int s, d;
    if (e < N_EDGES) { s = ei_src[e]; d = ei_dst[e]; }
    else             { s = d = (int)(e - N_EDGES); }
    int head = j >> 4;
    float alpha = logit[e * HEADS + head] / (den[(long)d * HEADS + head] + 1e-16f);
    atomicAdd(&aggout[(long)d * HID + j], alpha * xl[(long)s * HID + j]);
}

// ---------- h = gelu(aggout + cbias) + h ----------
__global__ void residual_kernel(const float* __restrict__ aggout, const float* __restrict__ cbias_l,
                                float* __restrict__ h) {
    int idx = blockIdx.x * blockDim.x + threadIdx.x;
    if (idx >= N_NODES * HID) return;
    int j = idx & 127;
    h[idx] = gelu_f(aggout[idx] + cbias_l[j]) + h[idx];
}

// ---------- pooling ----------
#define POOL_NODES 64
__global__ void pool_kernel(const float* __restrict__ h, const int* __restrict__ batch,
                            float* __restrict__ gsum, float* __restrict__ gcnt) {
    __shared__ float acc[N_GRAPHS][HID];
    __shared__ float cnt_sh[N_GRAPHS];
    int j = threadIdx.x;
    for (int g = 0; g < N_GRAPHS; ++g) acc[g][j] = 0.0f;
    if (j < N_GRAPHS) cnt_sh[j] = 0.0f;
    __syncthreads();
    int n0 = blockIdx.x * POOL_NODES;
    for (int i = 0; i < POOL_NODES; ++i) {
        int n = n0 + i;
        if (n >= N_NODES) break;
        int g = batch[n];
        acc[g][j] += h[(long)n * HID + j];
        if (j == 0) cnt_sh[g] += 1.0f;
    }
    __syncthreads();
    for (int g = 0; g < N_GRAPHS; ++g) atomicAdd(&gsum[g * HID + j], acc[g][j]);
    if (j < N_GRAPHS) atomicAdd(&gcnt[j], cnt_sh[j]);
}

// ---------- props head ----------
__global__ void props_kernel(const float* __restrict__ gsum, const float* __restrict__ gcnt,
                             const float* __restrict__ pW1, const float* __restrict__ pb1,
                             const float* __restrict__ pg, const float* __restrict__ pbe,
                             const float* __restrict__ pW2, const float* __restrict__ pb2,
                             float* __restrict__ out_props) {
    int g = blockIdx.x, j = threadIdx.x;
    __shared__ float feat[HID], red[HID], t2[HID];
    float c = fmaxf(gcnt[g], 1.0f);
    feat[j] = gsum[g * HID + j] / c;
    __syncthreads();
    float acc = pb1[j];
    for (int k = 0; k < HID; ++k) acc += feat[k] * pW1[k * HID + j];
    red[j] = acc;
    __syncthreads();
    for (int s = 64; s > 0; s >>= 1) { if (j < s) red[j] += red[j + s]; __syncthreads(); }
    float mean = red[0] * (1.0f / HID);
    __syncthreads();
    float dd = acc - mean;
    red[j] = dd * dd;
    __syncthreads();
    for (int s = 64; s > 0; s >>= 1) { if (j < s) red[j] += red[j + s]; __syncthreads(); }
    float var = red[0] * (1.0f / HID);
    t2[j] = gelu_f(dd * rsqrtf(var + LN_EPS) * pg[j] + pbe[j]);
    __syncthreads();
    if (j < COND) {
        float a = pb2[j];
        for (int k = 0; k < HID; ++k) a += t2[k] * pW2[k * COND + j];
        out_props[g * COND + j] = a;
    }
}

extern "C" void kernel_launch(void* const* d_in, const int* in_sizes, int n_in,
                              void* d_out, int out_size, void* d_ws, size_t ws_size,
                              hipStream_t stream) {
    const float* x        = (const float*)d_in[0];
    const float* edge_attr= (const float*)d_in[1];
    const float* t        = (const float*)d_in[2];
    const float* conds    = (const float*)d_in[3];
    const float* tW1      = (const float*)d_in[4];
    const float* tb1      = (const float*)d_in[5];
    const float* tW2      = (const float*)d_in[6];
    const float* tb2      = (const float*)d_in[7];
    const float* encW     = (const float*)d_in[8];
    const float* encb     = (const float*)d_in[9];
    const float* encg     = (const float*)d_in[10];
    const float* encbe    = (const float*)d_in[11];
    const float* eW       = (const float*)d_in[12];
    const float* eb       = (const float*)d_in[13];
    const float* eg       = (const float*)d_in[14];
    const float* ebe      = (const float*)d_in[15];
    const float* cWl      = (const float*)d_in[16];
    const float* cbl      = (const float*)d_in[17];
    const float* cWr      = (const float*)d_in[18];
    const float* cbr      = (const float*)d_in[19];
    const float* cWe      = (const float*)d_in[20];
    const float* catt     = (const float*)d_in[21];
    const float* cbias    = (const float*)d_in[22];
    const float* nW1      = (const float*)d_in[23];
    const float* nb1      = (const float*)d_in[24];
    const float* ng       = (const float*)d_in[25];
    const float* nbe      = (const float*)d_in[26];
    const float* nW2      = (const float*)d_in[27];
    const float* nb2      = (const float*)d_in[28];
    const float* pW1      = (const float*)d_in[29];
    const float* pb1      = (const float*)d_in[30];
    const float* pg       = (const float*)d_in[31];
    const float* pbe      = (const float*)d_in[32];
    const float* pW2      = (const float*)d_in[33];
    const float* pb2      = (const float*)d_in[34];
    const int* edge_index = (const int*)d_in[35];
    const int* batch      = (const int*)d_in[36];
    const int* ei_src = edge_index;
    const int* ei_dst = edge_index + N_EDGES;

    // workspace layout (~95 MB of f32)
    float* ws = (float*)d_ws;
    size_t off = 0;
    auto alloc = [&](size_t n) { float* p = ws + off; off += n; return p; };
    float* t_emb     = alloc((size_t)N_GRAPHS * HID);
    float* h         = alloc((size_t)N_NODES * HID);
    float* loop_attr = alloc((size_t)N_NODES * HID);
    float* cnt       = alloc((size_t)N_NODES);
    float* xl        = alloc((size_t)N_NODES * HID);
    float* xr        = alloc((size_t)N_NODES * HID);
    float* logit     = alloc((size_t)EF * HEADS);      // 4.08M floats
    float* mx        = alloc((size_t)N_NODES * HEADS);
    float* den       = alloc((size_t)N_NODES * HEADS);
    float* aggout    = alloc((size_t)N_NODES * HID);
    float* gsum      = alloc((size_t)N_GRAPHS * HID);
    float* gcnt      = alloc((size_t)N_GRAPHS);
    float* eWT4      = alloc((size_t)8 * HID * 4);            // k-tiled eW^T
    float* BT4       = alloc((size_t)NLAYERS * 32 * HID * 4); // k-tiled cWe^T per layer
    // aliases (disjoint lifetimes):
    float* xc   = logit;  // [N,72] = 2.16M floats, used only pre-layers; logit is 4.08M
    float* tmp1 = xl;     // used only post-layers
    (void)ws_size; (void)in_sizes; (void)n_in; (void)out_size;

    float* pred_noise = (float*)d_out;                              // [N,64]
    float* pred_props = (float*)d_out + (size_t)N_NODES * NODE_OUT; // [16,8]

    // 0. weight prep (k-tiled transposes for the att kernels)
    hipLaunchKernelGGL(prep_weights_kernel, dim3((NLAYERS * 32 * HID * 4 + 255) / 256), dim3(256),
                       0, stream, eW, cWe, eWT4, BT4);
    // 1. time MLP
    hipLaunchKernelGGL(time_mlp_kernel, dim3(N_GRAPHS), dim3(HID), 0, stream,
                       t, tW1, tb1, tW2, tb2, t_emb);
    // 2. concat
    hipLaunchKernelGGL(concat_kernel, dim3((N_NODES * 72 + 255) / 256), dim3(256), 0, stream,
                       x, conds, batch, xc);
    // 3. node encoder gemm + LN/GELU (+t_emb[batch])
    hipLaunchKernelGGL((gemm_kernel<HID, 8>), dim3(N_NODES / 8), dim3(HID), 0, stream,
                       xc, encW, encb, h, N_NODES, 72);
    hipLaunchKernelGGL(ln_gelu_kernel, dim3(N_NODES), dim3(HID), 0, stream,
                       h, encg, encbe, t_emb, batch);
    // 4. self-loop attr = segment-mean of encoded edge_attr over dst (encode fused, wave-parallel)
    hipLaunchKernelGGL(zero_kernel, dim3(1024), dim3(256), 0, stream,
                       loop_attr, (long)N_NODES * HID);
    hipLaunchKernelGGL(zero_kernel, dim3(64), dim3(256), 0, stream, cnt, (long)N_NODES);
    hipLaunchKernelGGL(edge_enc_loop3_kernel, dim3(N_EDGES / ETILE), dim3(256), 0, stream,
                       edge_attr, eWT4, eb, eg, ebe, ei_dst, loop_attr, cnt);
    hipLaunchKernelGGL(loop_div_kernel, dim3((N_NODES * HID + 255) / 256), dim3(256), 0, stream,
                       loop_attr, cnt);

    // 5. layers
    for (int l = 0; l < NLAYERS; ++l) {
        const float* cWl_l = cWl + (size_t)l * HID * HID;
        const float* cWr_l = cWr + (size_t)l * HID * HID;
        const float* BT4_l = BT4 + (size_t)l * 32 * HID * 4;
        const float* cbl_l = cbl + (size_t)l * HID;
        const float* cbr_l = cbr + (size_t)l * HID;
        const float* catt_l = catt + (size_t)l * HID;
        const float* cbias_l = cbias + (size_t)l * HID;

        hipLaunchKernelGGL((gemm_kernel<HID, 8>), dim3(N_NODES / 8), dim3(HID), 0, stream,
                           h, cWl_l, cbl_l, xl, N_NODES, HID);
        hipLaunchKernelGGL((gemm_kernel<HID, 8>), dim3(N_NODES / 8), dim3(HID), 0, stream,
                           h, cWr_l, cbr_l, xr, N_NODES, HID);
        hipLaunchKernelGGL(init_mx_den_kernel, dim3((N_NODES * HEADS + 255) / 256), dim3(256), 0,
                           stream, mx, den);
        hipLaunchKernelGGL((att_logit4_kernel<false>), dim3(N_EDGES / ETILE), dim3(256), 0, stream,
                           edge_attr, eWT4, eb, eg, ebe, loop_attr,
                           BT4_l, catt_l, xl, xr, ei_src, ei_dst, logit, mx);
        hipLaunchKernelGGL((att_logit4_kernel<true>), dim3((N_NODES + ETILE - 1) / ETILE), dim3(256),
                           0, stream,
                           edge_attr, eWT4, eb, eg, ebe, loop_attr,
                           BT4_l, catt_l, xl, xr, ei_src, ei_dst, logit, mx);
        hipLaunchKernelGGL(softmax_norm_kernel,
                           dim3((int)(((long)EF * HEADS + 255) / 256)), dim3(256), 0, stream,
                           ei_dst, mx, logit, den);
        hipLaunchKernelGGL(zero_kernel, dim3(1024), dim3(256), 0, stream,
                           aggout, (long)N_NODES * HID);
        hipLaunchKernelGGL(aggregate_kernel,
                           dim3((int)(((long)EF * HID + 255) / 256)), dim3(256), 0, stream,
                           logit, den, xl, ei_src, ei_dst, aggout);
        hipLaunchKernelGGL(residual_kernel, dim3((N_NODES * HID + 255) / 256), dim3(256), 0, stream,
                           aggout, cbias_l, h);
    }

    // 6. noise head
    hipLaunchKernelGGL((gemm_kernel<HID, 8>), dim3(N_NODES / 8), dim3(HID), 0, stream,
                       h, nW1, nb1, tmp1, N_NODES, HID);
    hipLaunchKernelGGL(ln_gelu_kernel, dim3(N_NODES), dim3(HID), 0, stream,
                       tmp1, ng, nbe, (const float*)nullptr, (const int*)nullptr);
    hipLaunchKernelGGL((gemm_kernel<NODE_OUT, 8>), dim3(N_NODES / 8), dim3(NODE_OUT), 0, stream,
                       tmp1, nW2, nb2, pred_noise, N_NODES, HID);

    // 7. pooling + props head
    hipLaunchKernelGGL(zero_kernel, dim3(4), dim3(256), 0, stream,
                       gsum, (long)N_GRAPHS * HID);
    hipLaunchKernelGGL(zero_kernel, dim3(1), dim3(64), 0, stream, gcnt, (long)N_GRAPHS);
    hipLaunchKernelGGL(pool_kernel, dim3((N_NODES + POOL_NODES - 1) / POOL_NODES), dim3(HID), 0,
                       stream, h, batch, gsum, gcnt);
    hipLaunchKernelGGL(props_kernel, dim3(N_GRAPHS), dim3(HID), 0, stream,
                       gsum, gcnt, pW1, pb1, pg, pbe, pW2, pb2, pred_props);
}

// Round 4
// 4296.434 us; speedup vs baseline: 1.4660x; 1.4660x over previous
//
#include <hip/hip_runtime.h>
#include <math.h>

#define N_NODES 30000
#define N_EDGES 480000
#define N_GRAPHS 16
#define HID 128
#define HEADS 8
#define HEAD_DIM 16
#define NODE_IN 64
#define EDGE_IN 32
#define COND 8
#define NODE_OUT 64
#define NLAYERS 4
#define EF (N_EDGES + N_NODES) /* 510000 */
#define LN_EPS 1e-5f

__device__ __forceinline__ float gelu_f(float x) {
    return 0.5f * x * (1.0f + erff(x * 0.70710678118654752440f));
}

__device__ __forceinline__ void atomicMaxF(float* addr, float val) {
    if (val >= 0.0f) {
        atomicMax((int*)addr, __float_as_int(val));
    } else {
        atomicMin((unsigned int*)addr, __float_as_uint(val));
    }
}

// ---------- generic zero ----------
__global__ void zero_kernel(float* __restrict__ p, long n) {
    long i = (long)blockIdx.x * blockDim.x + threadIdx.x;
    long stride = (long)gridDim.x * blockDim.x;
    for (; i < n; i += stride) p[i] = 0.0f;
}

// ---------- time MLP: t[16] -> t_emb[16,128] ----------
__global__ void time_mlp_kernel(const float* __restrict__ t,
                                const float* __restrict__ tW1, const float* __restrict__ tb1,
                                const float* __restrict__ tW2, const float* __restrict__ tb2,
                                float* __restrict__ t_emb) {
    __shared__ float hsh[HID];
    int b = blockIdx.x, j = threadIdx.x;
    float tv = t[b];
    hsh[j] = gelu_f(tv * tW1[j] + tb1[j]);
    __syncthreads();
    float acc = tb2[j];
    for (int k = 0; k < HID; ++k) acc += hsh[k] * tW2[k * HID + j];
    t_emb[b * HID + j] = acc;
}

// ---------- concat x(64) + conditions[batch](8) -> xc[N,72] ----------
__global__ void concat_kernel(const float* __restrict__ x, const float* __restrict__ cond,
                              const int* __restrict__ batch, float* __restrict__ xc) {
    int idx = blockIdx.x * blockDim.x + threadIdx.x;
    if (idx >= N_NODES * 72) return;
    int n = idx / 72, c = idx % 72;
    xc[idx] = (c < NODE_IN) ? x[n * NODE_IN + c] : cond[batch[n] * COND + (c - NODE_IN)];
}

// ---------- generic GEMM: C[M,NCOL] = A[M,K] @ B[K,NCOL] + bias ----------
// K must be a multiple of 4. Inner loop: float4 broadcast LDS reads.
template <int NCOL, int R>
__global__ void gemm_kernel(const float* __restrict__ A, const float* __restrict__ B,
                            const float* __restrict__ bias, float* __restrict__ C,
                            int M, int K) {
    __shared__ __align__(16) float sh[R * HID];
    int j = threadIdx.x;
    int row0 = blockIdx.x * R;
    int total = R * K;
    for (int i = j; i < total; i += NCOL) {
        int r = i / K, k = i - r * K;
        int row = row0 + r;
        sh[r * K + k] = (row < M) ? A[(long)row * K + k] : 0.0f;
    }
    __syncthreads();
    float acc[R];
    float bv = bias ? bias[j] : 0.0f;
#pragma unroll
    for (int r = 0; r < R; ++r) acc[r] = bv;
    int KB = K >> 2;
    for (int kb = 0; kb < KB; ++kb) {
        float w0 = B[(kb * 4 + 0) * NCOL + j];
        float w1 = B[(kb * 4 + 1) * NCOL + j];
        float w2 = B[(kb * 4 + 2) * NCOL + j];
        float w3 = B[(kb * 4 + 3) * NCOL + j];
#pragma unroll
        for (int r = 0; r < R; ++r) {
            float4 a = *(const float4*)&sh[r * K + kb * 4];
            acc[r] += a.x * w0 + a.y * w1 + a.z * w2 + a.w * w3;
        }
    }
#pragma unroll
    for (int r = 0; r < R; ++r) {
        int row = row0 + r;
        if (row < M) C[(long)row * NCOL + j] = acc[r];
    }
}

// ---------- in-place LayerNorm + GELU (+ optional t_emb[batch[row]]) ----------
__global__ void ln_gelu_kernel(float* __restrict__ X, const float* __restrict__ g,
                               const float* __restrict__ bta,
                               const float* __restrict__ t_emb, const int* __restrict__ batch) {
    int row = blockIdx.x, j = threadIdx.x;
    __shared__ float red[HID];
    float v = X[(long)row * HID + j];
    red[j] = v;
    __syncthreads();
    for (int s = 64; s > 0; s >>= 1) { if (j < s) red[j] += red[j + s]; __syncthreads(); }
    float mean = red[0] * (1.0f / HID);
    __syncthreads();
    float d = v - mean;
    red[j] = d * d;
    __syncthreads();
    for (int s = 64; s > 0; s >>= 1) { if (j < s) red[j] += red[j + s]; __syncthreads(); }
    float var = red[0] * (1.0f / HID);
    float y = gelu_f(d * rsqrtf(var + LN_EPS) * g[j] + bta[j]);
    if (t_emb) y += t_emb[batch[row] * HID + j];
    X[(long)row * HID + j] = y;
}

// ---------- fused: edge-encode + segment-sum into loop_sum/cnt ----------
// 128 threads, 8 edges/block. N_EDGES % 8 == 0 -> no guards.
template <int R>
__global__ void edge_enc_loop_kernel(const float* __restrict__ edge_attr,
                                     const float* __restrict__ eW, const float* __restrict__ eb,
                                     const float* __restrict__ eg, const float* __restrict__ ebe,
                                     const int* __restrict__ ei_dst,
                                     float* __restrict__ loop_sum, float* __restrict__ cnt) {
    __shared__ float red[R * HID];
    __shared__ __align__(16) float sattr[R * EDGE_IN];
    __shared__ int sdst[R];
    int j = threadIdx.x;
    long e0 = (long)blockIdx.x * R;
    if (j < R * EDGE_IN / 4)
        ((float4*)sattr)[j] = ((const float4*)(edge_attr + e0 * EDGE_IN))[j];
    if (j < R) sdst[j] = ei_dst[e0 + j];
    __syncthreads();
    float val[R];
    float ebv = eb[j];
#pragma unroll
    for (int r = 0; r < R; ++r) val[r] = ebv;
#pragma unroll
    for (int kb = 0; kb < EDGE_IN / 4; ++kb) {
        float w0 = eW[(kb * 4 + 0) * HID + j];
        float w1 = eW[(kb * 4 + 1) * HID + j];
        float w2 = eW[(kb * 4 + 2) * HID + j];
        float w3 = eW[(kb * 4 + 3) * HID + j];
#pragma unroll
        for (int r = 0; r < R; ++r) {
            float4 a = *(const float4*)&sattr[r * EDGE_IN + kb * 4];
            val[r] += a.x * w0 + a.y * w1 + a.z * w2 + a.w * w3;
        }
    }
#pragma unroll
    for (int r = 0; r < R; ++r) red[r * HID + j] = val[r];
    __syncthreads();
    for (int s = 64; s > 0; s >>= 1) {
        if (j < s) {
#pragma unroll
            for (int r = 0; r < R; ++r) red[r * HID + j] += red[r * HID + j + s];
        }
        __syncthreads();
    }
    float mean[R];
#pragma unroll
    for (int r = 0; r < R; ++r) mean[r] = red[r * HID] * (1.0f / HID);
    __syncthreads();
#pragma unroll
    for (int r = 0; r < R; ++r) { float d = val[r] - mean[r]; red[r * HID + j] = d * d; }
    __syncthreads();
    for (int s = 64; s > 0; s >>= 1) {
        if (j < s) {
#pragma unroll
            for (int r = 0; r < R; ++r) red[r * HID + j] += red[r * HID + j + s];
        }
        __syncthreads();
    }
    float egv = eg[j], bev = ebe[j];
#pragma unroll
    for (int r = 0; r < R; ++r) {
        float var = red[r * HID] * (1.0f / HID);
        float y = gelu_f((val[r] - mean[r]) * rsqrtf(var + LN_EPS) * egv + bev);
        int d = sdst[r];
        atomicAdd(&loop_sum[(long)d * HID + j], y);
        if (j == 0) atomicAdd(&cnt[d], 1.0f);
    }
}

__global__ void loop_div_kernel(float* __restrict__ loop_attr, const float* __restrict__ cnt) {
    int idx = blockIdx.x * blockDim.x + threadIdx.x;
    if (idx >= N_NODES * HID) return;
    int n = idx >> 7;
    loop_attr[idx] = loop_attr[idx] / fmaxf(cnt[n], 1.0f);
}

// ---------- init mx=-inf, den=0 ----------
__global__ void init_mx_den_kernel(float* __restrict__ mx, float* __restrict__ den) {
    int idx = blockIdx.x * blockDim.x + threadIdx.x;
    if (idx >= N_NODES * HEADS) return;
    mx[idx] = -INFINITY;
    den[idx] = 0.0f;
}

// ---------- fused: edge-encode recompute + em-GEMM + leakyrelu + logit + atomicMax ----------
// Round-0 structure (128 threads, R=8, VGPR~40-56, high occupancy), with float4 inner loops.
// Blocks are uniformly real-edge (e0 < N_EDGES) or self-loop (N_EDGES and N_NODES both %8==0).
template <int R>
__global__ void att_logit5_kernel(const float* __restrict__ edge_attr,
                                  const float* __restrict__ eW, const float* __restrict__ eb,
                                  const float* __restrict__ eg, const float* __restrict__ ebe,
                                  const float* __restrict__ loop_attr,
                                  const float* __restrict__ cWe_l,  /* [128,128] */
                                  const float* __restrict__ catt_l, /* [128] */
                                  const float* __restrict__ xl, const float* __restrict__ xr,
                                  const int* __restrict__ ei_src, const int* __restrict__ ei_dst,
                                  float* __restrict__ logit, float* __restrict__ mx) {
    __shared__ __align__(16) float sh[R * HID];
    __shared__ float red[R * HID];
    __shared__ __align__(16) float sattr[R * EDGE_IN];
    __shared__ int ssrc[R], sdst[R];
    int j = threadIdx.x;
    long e0 = (long)blockIdx.x * R;
    bool realblk = (e0 < N_EDGES);

    if (realblk && j < R * EDGE_IN / 4)
        ((float4*)sattr)[j] = ((const float4*)(edge_attr + e0 * EDGE_IN))[j];
    if (j < R) {
        long e = e0 + j;
        if (realblk) { ssrc[j] = ei_src[e]; sdst[j] = ei_dst[e]; }
        else         { ssrc[j] = sdst[j] = (int)(e - N_EDGES); }
    }
    __syncthreads();

    if (realblk) {
        // encode: val = edge_attr @ eW + eb  (float4 broadcast reads of sattr)
        float val[R];
        float ebv = eb[j];
#pragma unroll
        for (int r = 0; r < R; ++r) val[r] = ebv;
#pragma unroll
        for (int kb = 0; kb < EDGE_IN / 4; ++kb) {
            float w0 = eW[(kb * 4 + 0) * HID + j];
            float w1 = eW[(kb * 4 + 1) * HID + j];
            float w2 = eW[(kb * 4 + 2) * HID + j];
            float w3 = eW[(kb * 4 + 3) * HID + j];
#pragma unroll
            for (int r = 0; r < R; ++r) {
                float4 a = *(const float4*)&sattr[r * EDGE_IN + kb * 4];
                val[r] += a.x * w0 + a.y * w1 + a.z * w2 + a.w * w3;
            }
        }
        // LayerNorm stats (block tree) + GELU -> sh
#pragma unroll
        for (int r = 0; r < R; ++r) red[r * HID + j] = val[r];
        __syncthreads();
        for (int s = 64; s > 0; s >>= 1) {
            if (j < s) {
#pragma unroll
                for (int r = 0; r < R; ++r) red[r * HID + j] += red[r * HID + j + s];
            }
            __syncthreads();
        }
        float mean[R];
#pragma unroll
        for (int r = 0; r < R; ++r) mean[r] = red[r * HID] * (1.0f / HID);
        __syncthreads();
#pragma unroll
        for (int r = 0; r < R; ++r) { float d = val[r] - mean[r]; red[r * HID + j] = d * d; }
        __syncthreads();
        for (int s = 64; s > 0; s >>= 1) {
            if (j < s) {
#pragma unroll
                for (int r = 0; r < R; ++r) red[r * HID + j] += red[r * HID + j + s];
            }
            __syncthreads();
        }
        float egv = eg[j], bev = ebe[j];
#pragma unroll
        for (int r = 0; r < R; ++r) {
            float var = red[r * HID] * (1.0f / HID);
            sh[r * HID + j] = gelu_f((val[r] - mean[r]) * rsqrtf(var + LN_EPS) * egv + bev);
        }
    } else {
        // self-loop rows: loop_attr already final
#pragma unroll
        for (int r = 0; r < R; ++r)
            sh[r * HID + j] = loop_attr[(long)(e0 + r - N_EDGES) * HID + j];
    }
    __syncthreads();

    // em GEMM: acc[r] = (sh_row_r @ cWe)[j], float4 broadcast A reads
    float acc[R];
#pragma unroll
    for (int r = 0; r < R; ++r) acc[r] = 0.0f;
    for (int kb = 0; kb < HID / 4; ++kb) {
        float w0 = cWe_l[(kb * 4 + 0) * HID + j];
        float w1 = cWe_l[(kb * 4 + 1) * HID + j];
        float w2 = cWe_l[(kb * 4 + 2) * HID + j];
        float w3 = cWe_l[(kb * 4 + 3) * HID + j];
#pragma unroll
        for (int r = 0; r < R; ++r) {
            float4 a = *(const float4*)&sh[r * HID + kb * 4];
            acc[r] += a.x * w0 + a.y * w1 + a.z * w2 + a.w * w3;
        }
    }

    // logit + 16-lane head reduce + atomic max
    float cj = catt_l[j];
    int head = j >> 4;
#pragma unroll
    for (int r = 0; r < R; ++r) {
        long e = e0 + r;
        int s = ssrc[r], d = sdst[r];
        float m = xl[(long)s * HID + j] + xr[(long)d * HID + j] + acc[r];
        m = (m > 0.0f) ? m : 0.2f * m;
        float p = m * cj;
        p += __shfl_down(p, 8, 16);
        p += __shfl_down(p, 4, 16);
        p += __shfl_down(p, 2, 16);
        p += __shfl_down(p, 1, 16);
        if ((j & 15) == 0) {
            logit[e * HEADS + head] = p;
            atomicMaxF(&mx[(long)d * HEADS + head], p);
        }
    }
}

// ---------- exp(logit-mx), accumulate denominator ----------
__global__ void softmax_norm_kernel(const int* __restrict__ ei_dst, const float* __restrict__ mx,
                                    float* __restrict__ logit, float* __restrict__ den) {
    long idx = (long)blockIdx.x * blockDim.x + threadIdx.x;
    if (idx >= (long)EF * HEADS) return;
    long e = idx >> 3;
    int hh = (int)(idx & 7);
    int d = (e < N_EDGES) ? ei_dst[e] : (int)(e - N_EDGES);
    float ex = expf(logit[idx] - mx[(long)d * HEADS + hh]);
    logit[idx] = ex;
    atomicAdd(&den[(long)d * HEADS + hh], ex);
}

// ---------- alpha-weighted aggregation ----------
__global__ void aggregate_kernel(const float* __restrict__ logit, const float* __restrict__ den,
                                 const float* __restrict__ xl,
                                 const int* __restrict__ ei_src, const int* __restrict__ ei_dst,
                                 float* __restrict__ aggout) {
    long idx = (long)blockIdx.x * blockDim.x + threadIdx.x;
    if (idx >= (long)EF * HID) return;
    long e = idx >> 7;
    int j = (int)(idx & 127);
    int s, d;
    if (e < N_EDGES) { s = ei_src[e]; d = ei_dst[e]; }
    else             { s = d = (int)(e - N_EDGES); }
    int head = j >> 4;
    float alpha = logit[e * HEADS + head] / (den[(long)d * HEADS + head] + 1e-16f);
    atomicAdd(&aggout[(long)d * HID + j], alpha * xl[(long)s * HID + j]);
}

// ---------- h = gelu(aggout + cbias) + h ----------
__global__ void residual_kernel(const float* __restrict__ aggout, const float* __restrict__ cbias_l,
                                float* __restrict__ h) {
    int idx = blockIdx.x * blockDim.x + threadIdx.x;
    if (idx >= N_NODES * HID) return;
    int j = idx & 127;
    h[idx] = gelu_f(aggout[idx] + cbias_l[j]) + h[idx];
}

// ---------- pooling ----------
#define POOL_NODES 64
__global__ void pool_kernel(const float* __restrict__ h, const int* __restrict__ batch,
                            float* __restrict__ gsum, float* __restrict__ gcnt) {
    __shared__ float acc[N_GRAPHS][HID];
    __shared__ float cnt_sh[N_GRAPHS];
    int j = threadIdx.x;
    for (int g = 0; g < N_GRAPHS; ++g) acc[g][j] = 0.0f;
    if (j < N_GRAPHS) cnt_sh[j] = 0.0f;
    __syncthreads();
    int n0 = blockIdx.x * POOL_NODES;
    for (int i = 0; i < POOL_NODES; ++i) {
        int n = n0 + i;
        if (n >= N_NODES) break;
        int g = batch[n];
        acc[g][j] += h[(long)n * HID + j];
        if (j == 0) cnt_sh[g] += 1.0f;
    }
    __syncthreads();
    for (int g = 0; g < N_GRAPHS; ++g) atomicAdd(&gsum[g * HID + j], acc[g][j]);
    if (j < N_GRAPHS) atomicAdd(&gcnt[j], cnt_sh[j]);
}

// ---------- props head ----------
__global__ void props_kernel(const float* __restrict__ gsum, const float* __restrict__ gcnt,
                             const float* __restrict__ pW1, const float* __restrict__ pb1,
                             const float* __restrict__ pg, const float* __restrict__ pbe,
                             const float* __restrict__ pW2, const float* __restrict__ pb2,
                             float* __restrict__ out_props) {
    int g = blockIdx.x, j = threadIdx.x;
    __shared__ float feat[HID], red[HID], t2[HID];
    float c = fmaxf(gcnt[g], 1.0f);
    feat[j] = gsum[g * HID + j] / c;
    __syncthreads();
    float acc = pb1[j];
    for (int k = 0; k < HID; ++k) acc += feat[k] * pW1[k * HID + j];
    red[j] = acc;
    __syncthreads();
    for (int s = 64; s > 0; s >>= 1) { if (j < s) red[j] += red[j + s]; __syncthreads(); }
    float mean = red[0] * (1.0f / HID);
    __syncthreads();
    float dd = acc - mean;
    red[j] = dd * dd;
    __syncthreads();
    for (int s = 64; s > 0; s >>= 1) { if (j < s) red[j] += red[j + s]; __syncthreads(); }
    float var = red[0] * (1.0f / HID);
    t2[j] = gelu_f(dd * rsqrtf(var + LN_EPS) * pg[j] + pbe[j]);
    __syncthreads();
    if (j < COND) {
        float a = pb2[j];
        for (int k = 0; k < HID; ++k) a += t2[k] * pW2[k * COND + j];
        out_props[g * COND + j] = a;
    }
}

extern "C" void kernel_launch(void* const* d_in, const int* in_sizes, int n_in,
                              void* d_out, int out_size, void* d_ws, size_t ws_size,
                              hipStream_t stream) {
    const float* x        = (const float*)d_in[0];
    const float* edge_attr= (const float*)d_in[1];
    const float* t        = (const float*)d_in[2];
    const float* conds    = (const float*)d_in[3];
    const float* tW1      = (const float*)d_in[4];
    const float* tb1      = (const float*)d_in[5];
    const float* tW2      = (const float*)d_in[6];
    const float* tb2      = (const float*)d_in[7];
    const float* encW     = (const float*)d_in[8];
    const float* encb     = (const float*)d_in[9];
    const float* encg     = (const float*)d_in[10];
    const float* encbe    = (const float*)d_in[11];
    const float* eW       = (const float*)d_in[12];
    const float* eb       = (const float*)d_in[13];
    const float* eg       = (const float*)d_in[14];
    const float* ebe      = (const float*)d_in[15];
    const float* cWl      = (const float*)d_in[16];
    const float* cbl      = (const float*)d_in[17];
    const float* cWr      = (const float*)d_in[18];
    const float* cbr      = (const float*)d_in[19];
    const float* cWe      = (const float*)d_in[20];
    const float* catt     = (const float*)d_in[21];
    const float* cbias    = (const float*)d_in[22];
    const float* nW1      = (const float*)d_in[23];
    const float* nb1      = (const float*)d_in[24];
    const float* ng       = (const float*)d_in[25];
    const float* nbe      = (const float*)d_in[26];
    const float* nW2      = (const float*)d_in[27];
    const float* nb2      = (const float*)d_in[28];
    const float* pW1      = (const float*)d_in[29];
    const float* pb1      = (const float*)d_in[30];
    const float* pg       = (const float*)d_in[31];
    const float* pbe      = (const float*)d_in[32];
    const float* pW2      = (const float*)d_in[33];
    const float* pb2      = (const float*)d_in[34];
    const int* edge_index = (const int*)d_in[35];
    const int* batch      = (const int*)d_in[36];
    const int* ei_src = edge_index;
    const int* ei_dst = edge_index + N_EDGES;

    // workspace layout (~94 MB of f32)
    float* ws = (float*)d_ws;
    size_t off = 0;
    auto alloc = [&](size_t n) { float* p = ws + off; off += n; return p; };
    float* t_emb     = alloc((size_t)N_GRAPHS * HID);
    float* h         = alloc((size_t)N_NODES * HID);
    float* loop_attr = alloc((size_t)N_NODES * HID);
    float* cnt       = alloc((size_t)N_NODES);
    float* xl        = alloc((size_t)N_NODES * HID);
    float* xr        = alloc((size_t)N_NODES * HID);
    float* logit     = alloc((size_t)EF * HEADS);      // 4.08M floats
    float* mx        = alloc((size_t)N_NODES * HEADS);
    float* den       = alloc((size_t)N_NODES * HEADS);
    float* aggout    = alloc((size_t)N_NODES * HID);
    float* gsum      = alloc((size_t)N_GRAPHS * HID);
    float* gcnt      = alloc((size_t)N_GRAPHS);
    // aliases (disjoint lifetimes):
    float* xc   = logit;  // [N,72] = 2.16M floats, used only pre-layers; logit is 4.08M
    float* tmp1 = xl;     // used only post-layers
    (void)ws_size; (void)in_sizes; (void)n_in; (void)out_size;

    float* pred_noise = (float*)d_out;                              // [N,64]
    float* pred_props = (float*)d_out + (size_t)N_NODES * NODE_OUT; // [16,8]

    // 1. time MLP
    hipLaunchKernelGGL(time_mlp_kernel, dim3(N_GRAPHS), dim3(HID), 0, stream,
                       t, tW1, tb1, tW2, tb2, t_emb);
    // 2. concat
    hipLaunchKernelGGL(concat_kernel, dim3((N_NODES * 72 + 255) / 256), dim3(256), 0, stream,
                       x, conds, batch, xc);
    // 3. node encoder gemm + LN/GELU (+t_emb[batch])
    hipLaunchKernelGGL((gemm_kernel<HID, 8>), dim3(N_NODES / 8), dim3(HID), 0, stream,
                       xc, encW, encb, h, N_NODES, 72);
    hipLaunchKernelGGL(ln_gelu_kernel, dim3(N_NODES), dim3(HID), 0, stream,
                       h, encg, encbe, t_emb, batch);
    // 4. self-loop attr = segment-mean of encoded edge_attr over dst (encode fused)
    hipLaunchKernelGGL(zero_kernel, dim3(1024), dim3(256), 0, stream,
                       loop_attr, (long)N_NODES * HID);
    hipLaunchKernelGGL(zero_kernel, dim3(64), dim3(256), 0, stream, cnt, (long)N_NODES);
    hipLaunchKernelGGL((edge_enc_loop_kernel<8>), dim3(N_EDGES / 8), dim3(HID), 0, stream,
                       edge_attr, eW, eb, eg, ebe, ei_dst, loop_attr, cnt);
    hipLaunchKernelGGL(loop_div_kernel, dim3((N_NODES * HID + 255) / 256), dim3(256), 0, stream,
                       loop_attr, cnt);

    // 5. layers
    for (int l = 0; l < NLAYERS; ++l) {
        const float* cWl_l = cWl + (size_t)l * HID * HID;
        const float* cWr_l = cWr + (size_t)l * HID * HID;
        const float* cWe_l = cWe + (size_t)l * HID * HID;
        const float* cbl_l = cbl + (size_t)l * HID;
        const float* cbr_l = cbr + (size_t)l * HID;
        const float* catt_l = catt + (size_t)l * HID;
        const float* cbias_l = cbias + (size_t)l * HID;

        hipLaunchKernelGGL((gemm_kernel<HID, 8>), dim3(N_NODES / 8), dim3(HID), 0, stream,
                           h, cWl_l, cbl_l, xl, N_NODES, HID);
        hipLaunchKernelGGL((gemm_kernel<HID, 8>), dim3(N_NODES / 8), dim3(HID), 0, stream,
                           h, cWr_l, cbr_l, xr, N_NODES, HID);
        hipLaunchKernelGGL(init_mx_den_kernel, dim3((N_NODES * HEADS + 255) / 256), dim3(256), 0,
                           stream, mx, den);
        hipLaunchKernelGGL((att_logit5_kernel<8>), dim3(EF / 8), dim3(HID), 0, stream,
                           edge_attr, eW, eb, eg, ebe, loop_attr,
                           cWe_l, catt_l, xl, xr, ei_src, ei_dst, logit, mx);
        hipLaunchKernelGGL(softmax_norm_kernel,
                           dim3((int)(((long)EF * HEADS + 255) / 256)), dim3(256), 0, stream,
                           ei_dst, mx, logit, den);
        hipLaunchKernelGGL(zero_kernel, dim3(1024), dim3(256), 0, stream,
                           aggout, (long)N_NODES * HID);
        hipLaunchKernelGGL(aggregate_kernel,
                           dim3((int)(((long)EF * HID + 255) / 256)), dim3(256), 0, stream,
                           logit, den, xl, ei_src, ei_dst, aggout);
        hipLaunchKernelGGL(residual_kernel, dim3((N_NODES * HID + 255) / 256), dim3(256), 0, stream,
                           aggout, cbias_l, h);
    }

    // 6. noise head
    hipLaunchKernelGGL((gemm_kernel<HID, 8>), dim3(N_NODES / 8), dim3(HID), 0, stream,
                       h, nW1, nb1, tmp1, N_NODES, HID);
    hipLaunchKernelGGL(ln_gelu_kernel, dim3(N_NODES), dim3(HID), 0, stream,
                       tmp1, ng, nbe, (const float*)nullptr, (const int*)nullptr);
    hipLaunchKernelGGL((gemm_kernel<NODE_OUT, 8>), dim3(N_NODES / 8), dim3(NODE_OUT), 0, stream,
                       tmp1, nW2, nb2, pred_noise, N_NODES, HID);

    // 7. pooling + props head
    hipLaunchKernelGGL(zero_kernel, dim3(4), dim3(256), 0, stream,
                       gsum, (long)N_GRAPHS * HID);
    hipLaunchKernelGGL(zero_kernel, dim3(1), dim3(64), 0, stream, gcnt, (long)N_GRAPHS);
    hipLaunchKernelGGL(pool_kernel, dim3((N_NODES + POOL_NODES - 1) / POOL_NODES), dim3(HID), 0,
                       stream, h, batch, gsum, gcnt);
    hipLaunchKernelGGL(props_kernel, dim3(N_GRAPHS), dim3(HID), 0, stream,
                       gsum, gcnt, pW1, pb1, pg, pbe, pW2, pb2, pred_props);
}

// Round 6
// 4285.820 us; speedup vs baseline: 1.4696x; 1.0025x over previous
//
#include <hip/hip_runtime.h>
#include <math.h>

#define N_NODES 30000
#define N_EDGES 480000
#define N_GRAPHS 16
#define HID 128
#define HEADS 8
#define HEAD_DIM 16
#define NODE_IN 64
#define EDGE_IN 32
#define COND 8
#define NODE_OUT 64
#define NLAYERS 4
#define EF (N_EDGES + N_NODES) /* 510000 */
#define LN_EPS 1e-5f

__device__ __forceinline__ float gelu_f(float x) {
    return 0.5f * x * (1.0f + erff(x * 0.70710678118654752440f));
}

__device__ __forceinline__ void atomicMaxF(float* addr, float val) {
    if (val >= 0.0f) {
        atomicMax((int*)addr, __float_as_int(val));
    } else {
        atomicMin((unsigned int*)addr, __float_as_uint(val));
    }
}

// ---------- generic zero ----------
__global__ void zero_kernel(float* __restrict__ p, long n) {
    long i = (long)blockIdx.x * blockDim.x + threadIdx.x;
    long stride = (long)gridDim.x * blockDim.x;
    for (; i < n; i += stride) p[i] = 0.0f;
}

// ---------- time MLP: t[16] -> t_emb[16,128] ----------
__global__ void time_mlp_kernel(const float* __restrict__ t,
                                const float* __restrict__ tW1, const float* __restrict__ tb1,
                                const float* __restrict__ tW2, const float* __restrict__ tb2,
                                float* __restrict__ t_emb) {
    __shared__ float hsh[HID];
    int b = blockIdx.x, j = threadIdx.x;
    float tv = t[b];
    hsh[j] = gelu_f(tv * tW1[j] + tb1[j]);
    __syncthreads();
    float acc = tb2[j];
    for (int k = 0; k < HID; ++k) acc += hsh[k] * tW2[k * HID + j];
    t_emb[b * HID + j] = acc;
}

// ---------- concat x(64) + conditions[batch](8) -> xc[N,72] ----------
__global__ void concat_kernel(const float* __restrict__ x, const float* __restrict__ cond,
                              const int* __restrict__ batch, float* __restrict__ xc) {
    int idx = blockIdx.x * blockDim.x + threadIdx.x;
    if (idx >= N_NODES * 72) return;
    int n = idx / 72, c = idx % 72;
    xc[idx] = (c < NODE_IN) ? x[n * NODE_IN + c] : cond[batch[n] * COND + (c - NODE_IN)];
}

// ---------- generic GEMM: C[M,NCOL] = A[M,K] @ B[K,NCOL] + bias ----------
// K must be a multiple of 4. Inner loop: float4 broadcast LDS reads.
template <int NCOL, int R>
__global__ void gemm_kernel(const float* __restrict__ A, const float* __restrict__ B,
                            const float* __restrict__ bias, float* __restrict__ C,
                            int M, int K) {
    __shared__ __align__(16) float sh[R * HID];
    int j = threadIdx.x;
    int row0 = blockIdx.x * R;
    int total = R * K;
    for (int i = j; i < total; i += NCOL) {
        int r = i / K, k = i - r * K;
        int row = row0 + r;
        sh[r * K + k] = (row < M) ? A[(long)row * K + k] : 0.0f;
    }
    __syncthreads();
    float acc[R];
    float bv = bias ? bias[j] : 0.0f;
#pragma unroll
    for (int r = 0; r < R; ++r) acc[r] = bv;
    int KB = K >> 2;
    for (int kb = 0; kb < KB; ++kb) {
        float w0 = B[(kb * 4 + 0) * NCOL + j];
        float w1 = B[(kb * 4 + 1) * NCOL + j];
        float w2 = B[(kb * 4 + 2) * NCOL + j];
        float w3 = B[(kb * 4 + 3) * NCOL + j];
#pragma unroll
        for (int r = 0; r < R; ++r) {
            float4 a = *(const float4*)&sh[r * K + kb * 4];
            acc[r] += a.x * w0 + a.y * w1 + a.z * w2 + a.w * w3;
        }
    }
#pragma unroll
    for (int r = 0; r < R; ++r) {
        int row = row0 + r;
        if (row < M) C[(long)row * NCOL + j] = acc[r];
    }
}

// ---------- in-place LayerNorm + GELU (+ optional t_emb[batch[row]]) ----------
__global__ void ln_gelu_kernel(float* __restrict__ X, const float* __restrict__ g,
                               const float* __restrict__ bta,
                               const float* __restrict__ t_emb, const int* __restrict__ batch) {
    int row = blockIdx.x, j = threadIdx.x;
    __shared__ float red[HID];
    float v = X[(long)row * HID + j];
    red[j] = v;
    __syncthreads();
    for (int s = 64; s > 0; s >>= 1) { if (j < s) red[j] += red[j + s]; __syncthreads(); }
    float mean = red[0] * (1.0f / HID);
    __syncthreads();
    float d = v - mean;
    red[j] = d * d;
    __syncthreads();
    for (int s = 64; s > 0; s >>= 1) { if (j < s) red[j] += red[j + s]; __syncthreads(); }
    float var = red[0] * (1.0f / HID);
    float y = gelu_f(d * rsqrtf(var + LN_EPS) * g[j] + bta[j]);
    if (t_emb) y += t_emb[batch[row] * HID + j];
    X[(long)row * HID + j] = y;
}

// ---------- fused: edge-encode + segment-sum into loop_sum/cnt ----------
// 128 threads, 8 edges/block. N_EDGES % 8 == 0 -> no guards.
// STORE_EA: additionally write encoded rows to ea [N_EDGES,128].
template <int R, bool STORE_EA>
__global__ void edge_enc_loop_kernel(const float* __restrict__ edge_attr,
                                     const float* __restrict__ eW, const float* __restrict__ eb,
                                     const float* __restrict__ eg, const float* __restrict__ ebe,
                                     const int* __restrict__ ei_dst,
                                     float* __restrict__ loop_sum, float* __restrict__ cnt,
                                     float* __restrict__ ea) {
    __shared__ float red[R * HID];
    __shared__ __align__(16) float sattr[R * EDGE_IN];
    __shared__ int sdst[R];
    int j = threadIdx.x;
    long e0 = (long)blockIdx.x * R;
    if (j < R * EDGE_IN / 4)
        ((float4*)sattr)[j] = ((const float4*)(edge_attr + e0 * EDGE_IN))[j];
    if (j < R) sdst[j] = ei_dst[e0 + j];
    __syncthreads();
    float val[R];
    float ebv = eb[j];
#pragma unroll
    for (int r = 0; r < R; ++r) val[r] = ebv;
#pragma unroll
    for (int kb = 0; kb < EDGE_IN / 4; ++kb) {
        float w0 = eW[(kb * 4 + 0) * HID + j];
        float w1 = eW[(kb * 4 + 1) * HID + j];
        float w2 = eW[(kb * 4 + 2) * HID + j];
        float w3 = eW[(kb * 4 + 3) * HID + j];
#pragma unroll
        for (int r = 0; r < R; ++r) {
            float4 a = *(const float4*)&sattr[r * EDGE_IN + kb * 4];
            val[r] += a.x * w0 + a.y * w1 + a.z * w2 + a.w * w3;
        }
    }
#pragma unroll
    for (int r = 0; r < R; ++r) red[r * HID + j] = val[r];
    __syncthreads();
    for (int s = 64; s > 0; s >>= 1) {
        if (j < s) {
#pragma unroll
            for (int r = 0; r < R; ++r) red[r * HID + j] += red[r * HID + j + s];
        }
        __syncthreads();
    }
    float mean[R];
#pragma unroll
    for (int r = 0; r < R; ++r) mean[r] = red[r * HID] * (1.0f / HID);
    __syncthreads();
#pragma unroll
    for (int r = 0; r < R; ++r) { float d = val[r] - mean[r]; red[r * HID + j] = d * d; }
    __syncthreads();
    for (int s = 64; s > 0; s >>= 1) {
        if (j < s) {
#pragma unroll
            for (int r = 0; r < R; ++r) red[r * HID + j] += red[r * HID + j + s];
        }
        __syncthreads();
    }
    float egv = eg[j], bev = ebe[j];
#pragma unroll
    for (int r = 0; r < R; ++r) {
        float var = red[r * HID] * (1.0f / HID);
        float y = gelu_f((val[r] - mean[r]) * rsqrtf(var + LN_EPS) * egv + bev);
        int d = sdst[r];
        if (STORE_EA) ea[(e0 + r) * HID + j] = y;
        atomicAdd(&loop_sum[(long)d * HID + j], y);
        if (j == 0) atomicAdd(&cnt[d], 1.0f);
    }
}

__global__ void loop_div_kernel(float* __restrict__ loop_attr, const float* __restrict__ cnt) {
    int idx = blockIdx.x * blockDim.x + threadIdx.x;
    if (idx >= N_NODES * HID) return;
    int n = idx >> 7;
    loop_attr[idx] = loop_attr[idx] / fmaxf(cnt[n], 1.0f);
}

// ---------- init mx=-inf, den=0 ----------
__global__ void init_mx_den_kernel(float* __restrict__ mx, float* __restrict__ den) {
    int idx = blockIdx.x * blockDim.x + threadIdx.x;
    if (idx >= N_NODES * HEADS) return;
    mx[idx] = -INFINITY;
    den[idx] = 0.0f;
}

// ---------- fused: edge-encode recompute + em-GEMM + leakyrelu + logit + atomicMax ----------
// Round-4 proven structure (128 threads, R=8). Fallback path when workspace is small.
template <int R>
__global__ void att_logit5_kernel(const float* __restrict__ edge_attr,
                                  const float* __restrict__ eW, const float* __restrict__ eb,
                                  const float* __restrict__ eg, const float* __restrict__ ebe,
                                  const float* __restrict__ loop_attr,
                                  const float* __restrict__ cWe_l,  /* [128,128] */
                                  const float* __restrict__ catt_l, /* [128] */
                                  const float* __restrict__ xl, const float* __restrict__ xr,
                                  const int* __restrict__ ei_src, const int* __restrict__ ei_dst,
                                  float* __restrict__ logit, float* __restrict__ mx) {
    __shared__ __align__(16) float sh[R * HID];
    __shared__ float red[R * HID];
    __shared__ __align__(16) float sattr[R * EDGE_IN];
    __shared__ int ssrc[R], sdst[R];
    int j = threadIdx.x;
    long e0 = (long)blockIdx.x * R;
    bool realblk = (e0 < N_EDGES);

    if (realblk && j < R * EDGE_IN / 4)
        ((float4*)sattr)[j] = ((const float4*)(edge_attr + e0 * EDGE_IN))[j];
    if (j < R) {
        long e = e0 + j;
        if (realblk) { ssrc[j] = ei_src[e]; sdst[j] = ei_dst[e]; }
        else         { ssrc[j] = sdst[j] = (int)(e - N_EDGES); }
    }
    __syncthreads();

    if (realblk) {
        float val[R];
        float ebv = eb[j];
#pragma unroll
        for (int r = 0; r < R; ++r) val[r] = ebv;
#pragma unroll
        for (int kb = 0; kb < EDGE_IN / 4; ++kb) {
            float w0 = eW[(kb * 4 + 0) * HID + j];
            float w1 = eW[(kb * 4 + 1) * HID + j];
            float w2 = eW[(kb * 4 + 2) * HID + j];
            float w3 = eW[(kb * 4 + 3) * HID + j];
#pragma unroll
            for (int r = 0; r < R; ++r) {
                float4 a = *(const float4*)&sattr[r * EDGE_IN + kb * 4];
                val[r] += a.x * w0 + a.y * w1 + a.z * w2 + a.w * w3;
            }
        }
#pragma unroll
        for (int r = 0; r < R; ++r) red[r * HID + j] = val[r];
        __syncthreads();
        for (int s = 64; s > 0; s >>= 1) {
            if (j < s) {
#pragma unroll
                for (int r = 0; r < R; ++r) red[r * HID + j] += red[r * HID + j + s];
            }
            __syncthreads();
        }
        float mean[R];
#pragma unroll
        for (int r = 0; r < R; ++r) mean[r] = red[r * HID] * (1.0f / HID);
        __syncthreads();
#pragma unroll
        for (int r = 0; r < R; ++r) { float d = val[r] - mean[r]; red[r * HID + j] = d * d; }
        __syncthreads();
        for (int s = 64; s > 0; s >>= 1) {
            if (j < s) {
#pragma unroll
                for (int r = 0; r < R; ++r) red[r * HID + j] += red[r * HID + j + s];
            }
            __syncthreads();
        }
        float egv = eg[j], bev = ebe[j];
#pragma unroll
        for (int r = 0; r < R; ++r) {
            float var = red[r * HID] * (1.0f / HID);
            sh[r * HID + j] = gelu_f((val[r] - mean[r]) * rsqrtf(var + LN_EPS) * egv + bev);
        }
    } else {
#pragma unroll
        for (int r = 0; r < R; ++r)
            sh[r * HID + j] = loop_attr[(long)(e0 + r - N_EDGES) * HID + j];
    }
    __syncthreads();

    float acc[R];
#pragma unroll
    for (int r = 0; r < R; ++r) acc[r] = 0.0f;
    for (int kb = 0; kb < HID / 4; ++kb) {
        float w0 = cWe_l[(kb * 4 + 0) * HID + j];
        float w1 = cWe_l[(kb * 4 + 1) * HID + j];
        float w2 = cWe_l[(kb * 4 + 2) * HID + j];
        float w3 = cWe_l[(kb * 4 + 3) * HID + j];
#pragma unroll
        for (int r = 0; r < R; ++r) {
            float4 a = *(const float4*)&sh[r * HID + kb * 4];
            acc[r] += a.x * w0 + a.y * w1 + a.z * w2 + a.w * w3;
        }
    }

    float cj = catt_l[j];
    int head = j >> 4;
#pragma unroll
    for (int r = 0; r < R; ++r) {
        long e = e0 + r;
        int s = ssrc[r], d = sdst[r];
        float m = xl[(long)s * HID + j] + xr[(long)d * HID + j] + acc[r];
        m = (m > 0.0f) ? m : 0.2f * m;
        float p = m * cj;
        p += __shfl_down(p, 8, 16);
        p += __shfl_down(p, 4, 16);
        p += __shfl_down(p, 2, 16);
        p += __shfl_down(p, 1, 16);
        if ((j & 15) == 0) {
            logit[e * HEADS + head] = p;
            atomicMaxF(&mx[(long)d * HEADS + head], p);
        }
    }
}

// ---------- att kernel with PRECOMPUTED ea: stage -> em GEMM -> logit ----------
// Same shape as att_logit5 but the encode phase is replaced by a coalesced float4 stream
// of the memoized ea rows (layer-invariant). LDS: sh (4KB) + idx only.
template <int R>
__global__ void att_logit6_kernel(const float* __restrict__ ea,        /* [N_EDGES,128] */
                                  const float* __restrict__ loop_attr, /* [N_NODES,128] */
                                  const float* __restrict__ cWe_l,     /* [128,128] */
                                  const float* __restrict__ catt_l,    /* [128] */
                                  const float* __restrict__ xl, const float* __restrict__ xr,
                                  const int* __restrict__ ei_src, const int* __restrict__ ei_dst,
                                  float* __restrict__ logit, float* __restrict__ mx) {
    __shared__ __align__(16) float sh[R * HID];
    __shared__ int ssrc[R], sdst[R];
    int j = threadIdx.x;
    long e0 = (long)blockIdx.x * R;
    bool realblk = (e0 < N_EDGES);

    // stage R rows of ea / loop_attr into LDS, coalesced float4 (R*32 float4s, 128 threads)
    const float* srcp = realblk ? (ea + e0 * HID) : (loop_attr + (e0 - N_EDGES) * HID);
    const float4* s4 = (const float4*)srcp;
    ((float4*)sh)[j]       = s4[j];
    ((float4*)sh)[j + HID] = s4[j + HID];
    if (j < R) {
        long e = e0 + j;
        if (realblk) { ssrc[j] = ei_src[e]; sdst[j] = ei_dst[e]; }
        else         { ssrc[j] = sdst[j] = (int)(e - N_EDGES); }
    }
    __syncthreads();

    // em GEMM: acc[r] = (sh_row_r @ cWe)[j]
    float acc[R];
#pragma unroll
    for (int r = 0; r < R; ++r) acc[r] = 0.0f;
    for (int kb = 0; kb < HID / 4; ++kb) {
        float w0 = cWe_l[(kb * 4 + 0) * HID + j];
        float w1 = cWe_l[(kb * 4 + 1) * HID + j];
        float w2 = cWe_l[(kb * 4 + 2) * HID + j];
        float w3 = cWe_l[(kb * 4 + 3) * HID + j];
#pragma unroll
        for (int r = 0; r < R; ++r) {
            float4 a = *(const float4*)&sh[r * HID + kb * 4];
            acc[r] += a.x * w0 + a.y * w1 + a.z * w2 + a.w * w3;
        }
    }

    float cj = catt_l[j];
    int head = j >> 4;
#pragma unroll
    for (int r = 0; r < R; ++r) {
        long e = e0 + r;
        int s = ssrc[r], d = sdst[r];
        float m = xl[(long)s * HID + j] + xr[(long)d * HID + j] + acc[r];
        m = (m > 0.0f) ? m : 0.2f * m;
        float p = m * cj;
        p += __shfl_down(p, 8, 16);
        p += __shfl_down(p, 4, 16);
        p += __shfl_down(p, 2, 16);
        p += __shfl_down(p, 1, 16);
        if ((j & 15) == 0) {
            logit[e * HEADS + head] = p;
            atomicMaxF(&mx[(long)d * HEADS + head], p);
        }
    }
}

// ---------- exp(logit-mx), accumulate denominator ----------
__global__ void softmax_norm_kernel(const int* __restrict__ ei_dst, const float* __restrict__ mx,
                                    float* __restrict__ logit, float* __restrict__ den) {
    long idx = (long)blockIdx.x * blockDim.x + threadIdx.x;
    if (idx >= (long)EF * HEADS) return;
    long e = idx >> 3;
    int hh = (int)(idx & 7);
    int d = (e < N_EDGES) ? ei_dst[e] : (int)(e - N_EDGES);
    float ex = expf(logit[idx] - mx[(long)d * HEADS + hh]);
    logit[idx] = ex;
    atomicAdd(&den[(long)d * HEADS + hh], ex);
}

// ---------- alpha-weighted aggregation ----------
__global__ void aggregate_kernel(const float* __restrict__ logit, const float* __restrict__ den,
                                 const float* __restrict__ xl,
                                 const int* __restrict__ ei_src, const int* __restrict__ ei_dst,
                                 float* __restrict__ aggout) {
    long idx = (long)blockIdx.x * blockDim.x + threadIdx.x;
    if (idx >= (long)EF * HID) return;
    long e = idx >> 7;
    int j = (int)(idx & 127);
    int s, d;
    if (e < N_EDGES) { s = ei_src[e]; d = ei_dst[e]; }
    else             { s = d = (int)(e - N_EDGES); }
    int head = j >> 4;
    float alpha = logit[e * HEADS + head] / (den[(long)d * HEADS + head] + 1e-16f);
    atomicAdd(&aggout[(long)d * HID + j], alpha * xl[(long)s * HID + j]);
}

// ---------- h = gelu(aggout + cbias) + h ----------
__global__ void residual_kernel(const float* __restrict__ aggout, const float* __restrict__ cbias_l,
                                float* __restrict__ h) {
    int idx = blockIdx.x * blockDim.x + threadIdx.x;
    if (idx >= N_NODES * HID) return;
    int j = idx & 127;
    h[idx] = gelu_f(aggout[idx] + cbias_l[j]) + h[idx];
}

// ---------- pooling ----------
#define POOL_NODES 64
__global__ void pool_kernel(const float* __restrict__ h, const int* __restrict__ batch,
                            float* __restrict__ gsum, float* __restrict__ gcnt) {
    __shared__ float acc[N_GRAPHS][HID];
    __shared__ float cnt_sh[N_GRAPHS];
    int j = threadIdx.x;
    for (int g = 0; g < N_GRAPHS; ++g) acc[g][j] = 0.0f;
    if (j < N_GRAPHS) cnt_sh[j] = 0.0f;
    __syncthreads();
    int n0 = blockIdx.x * POOL_NODES;
    for (int i = 0; i < POOL_NODES; ++i) {
        int n = n0 + i;
        if (n >= N_NODES) break;
        int g = batch[n];
        acc[g][j] += h[(long)n * HID + j];
        if (j == 0) cnt_sh[g] += 1.0f;
    }
    __syncthreads();
    for (int g = 0; g < N_GRAPHS; ++g) atomicAdd(&gsum[g * HID + j], acc[g][j]);
    if (j < N_GRAPHS) atomicAdd(&gcnt[j], cnt_sh[j]);
}

// ---------- props head ----------
__global__ void props_kernel(const float* __restrict__ gsum, const float* __restrict__ gcnt,
                             const float* __restrict__ pW1, const float* __restrict__ pb1,
                             const float* __restrict__ pg, const float* __restrict__ pbe,
                             const float* __restrict__ pW2, const float* __restrict__ pb2,
                             float* __restrict__ out_props) {
    int g = blockIdx.x, j = threadIdx.x;
    __shared__ float feat[HID], red[HID], t2[HID];
    float c = fmaxf(gcnt[g], 1.0f);
    feat[j] = gsum[g * HID + j] / c;
    __syncthreads();
    float acc = pb1[j];
    for (int k = 0; k < HID; ++k) acc += feat[k] * pW1[k * HID + j];
    red[j] = acc;
    __syncthreads();
    for (int s = 64; s > 0; s >>= 1) { if (j < s) red[j] += red[j + s]; __syncthreads(); }
    float mean = red[0] * (1.0f / HID);
    __syncthreads();
    float dd = acc - mean;
    red[j] = dd * dd;
    __syncthreads();
    for (int s = 64; s > 0; s >>= 1) { if (j < s) red[j] += red[j + s]; __syncthreads(); }
    float var = red[0] * (1.0f / HID);
    t2[j] = gelu_f(dd * rsqrtf(var + LN_EPS) * pg[j] + pbe[j]);
    __syncthreads();
    if (j < COND) {
        float a = pb2[j];
        for (int k = 0; k < HID; ++k) a += t2[k] * pW2[k * COND + j];
        out_props[g * COND + j] = a;
    }
}

extern "C" void kernel_launch(void* const* d_in, const int* in_sizes, int n_in,
                              void* d_out, int out_size, void* d_ws, size_t ws_size,
                              hipStream_t stream) {
    const float* x        = (const float*)d_in[0];
    const float* edge_attr= (const float*)d_in[1];
    const float* t        = (const float*)d_in[2];
    const float* conds    = (const float*)d_in[3];
    const float* tW1      = (const float*)d_in[4];
    const float* tb1      = (const float*)d_in[5];
    const float* tW2      = (const float*)d_in[6];
    const float* tb2      = (const float*)d_in[7];
    const float* encW     = (const float*)d_in[8];
    const float* encb     = (const float*)d_in[9];
    const float* encg     = (const float*)d_in[10];
    const float* encbe    = (const float*)d_in[11];
    const float* eW       = (const float*)d_in[12];
    const float* eb       = (const float*)d_in[13];
    const float* eg       = (const float*)d_in[14];
    const float* ebe      = (const float*)d_in[15];
    const float* cWl      = (const float*)d_in[16];
    const float* cbl      = (const float*)d_in[17];
    const float* cWr      = (const float*)d_in[18];
    const float* cbr      = (const float*)d_in[19];
    const float* cWe      = (const float*)d_in[20];
    const float* catt     = (const float*)d_in[21];
    const float* cbias    = (const float*)d_in[22];
    const float* nW1      = (const float*)d_in[23];
    const float* nb1      = (const float*)d_in[24];
    const float* ng       = (const float*)d_in[25];
    const float* nbe      = (const float*)d_in[26];
    const float* nW2      = (const float*)d_in[27];
    const float* nb2      = (const float*)d_in[28];
    const float* pW1      = (const float*)d_in[29];
    const float* pb1      = (const float*)d_in[30];
    const float* pg       = (const float*)d_in[31];
    const float* pbe      = (const float*)d_in[32];
    const float* pW2      = (const float*)d_in[33];
    const float* pb2      = (const float*)d_in[34];
    const int* edge_index = (const int*)d_in[35];
    const int* batch      = (const int*)d_in[36];
    const int* ei_src = edge_index;
    const int* ei_dst = edge_index + N_EDGES;

    // workspace layout (base ~95 MB of f32; +246 MB for memoized ea if available)
    float* ws = (float*)d_ws;
    size_t off = 0;
    auto alloc = [&](size_t n) { float* p = ws + off; off += n; return p; };
    float* t_emb     = alloc((size_t)N_GRAPHS * HID);
    float* h         = alloc((size_t)N_NODES * HID);
    float* loop_attr = alloc((size_t)N_NODES * HID);
    float* cnt       = alloc((size_t)N_NODES);
    float* xl        = alloc((size_t)N_NODES * HID);
    float* xr        = alloc((size_t)N_NODES * HID);
    float* logit     = alloc((size_t)EF * HEADS);      // 4.08M floats
    float* mx        = alloc((size_t)N_NODES * HEADS);
    float* den       = alloc((size_t)N_NODES * HEADS);
    float* aggout    = alloc((size_t)N_NODES * HID);
    float* gsum      = alloc((size_t)N_GRAPHS * HID);
    float* gcnt      = alloc((size_t)N_GRAPHS);
    size_t base_floats = off;
    float* ea = ws + base_floats;                       // [N_EDGES,128] if it fits
    bool use_ea = ws_size >= (base_floats + (size_t)N_EDGES * HID) * sizeof(float);
    // aliases (disjoint lifetimes):
    float* xc   = logit;  // [N,72] = 2.16M floats, used only pre-layers; logit is 4.08M
    float* tmp1 = xl;     // used only post-layers
    (void)in_sizes; (void)n_in; (void)out_size;

    float* pred_noise = (float*)d_out;                              // [N,64]
    float* pred_props = (float*)d_out + (size_t)N_NODES * NODE_OUT; // [16,8]

    // 1. time MLP
    hipLaunchKernelGGL(time_mlp_kernel, dim3(N_GRAPHS), dim3(HID), 0, stream,
                       t, tW1, tb1, tW2, tb2, t_emb);
    // 2. concat
    hipLaunchKernelGGL(concat_kernel, dim3((N_NODES * 72 + 255) / 256), dim3(256), 0, stream,
                       x, conds, batch, xc);
    // 3. node encoder gemm + LN/GELU (+t_emb[batch])
    hipLaunchKernelGGL((gemm_kernel<HID, 8>), dim3(N_NODES / 8), dim3(HID), 0, stream,
                       xc, encW, encb, h, N_NODES, 72);
    hipLaunchKernelGGL(ln_gelu_kernel, dim3(N_NODES), dim3(HID), 0, stream,
                       h, encg, encbe, t_emb, batch);
    // 4. edge encode (memoized into ea when ws allows) + self-loop segment-mean
    hipLaunchKernelGGL(zero_kernel, dim3(1024), dim3(256), 0, stream,
                       loop_attr, (long)N_NODES * HID);
    hipLaunchKernelGGL(zero_kernel, dim3(64), dim3(256), 0, stream, cnt, (long)N_NODES);
    if (use_ea) {
        hipLaunchKernelGGL((edge_enc_loop_kernel<8, true>), dim3(N_EDGES / 8), dim3(HID), 0, stream,
                           edge_attr, eW, eb, eg, ebe, ei_dst, loop_attr, cnt, ea);
    } else {
        hipLaunchKernelGGL((edge_enc_loop_kernel<8, false>), dim3(N_EDGES / 8), dim3(HID), 0, stream,
                           edge_attr, eW, eb, eg, ebe, ei_dst, loop_attr, cnt, (float*)nullptr);
    }
    hipLaunchKernelGGL(loop_div_kernel, dim3((N_NODES * HID + 255) / 256), dim3(256), 0, stream,
                       loop_attr, cnt);

    // 5. layers
    for (int l = 0; l < NLAYERS; ++l) {
        const float* cWl_l = cWl + (size_t)l * HID * HID;
        const float* cWr_l = cWr + (size_t)l * HID * HID;
        const float* cWe_l = cWe + (size_t)l * HID * HID;
        const float* cbl_l = cbl + (size_t)l * HID;
        const float* cbr_l = cbr + (size_t)l * HID;
        const float* catt_l = catt + (size_t)l * HID;
        const float* cbias_l = cbias + (size_t)l * HID;

        hipLaunchKernelGGL((gemm_kernel<HID, 8>), dim3(N_NODES / 8), dim3(HID), 0, stream,
                           h, cWl_l, cbl_l, xl, N_NODES, HID);
        hipLaunchKernelGGL((gemm_kernel<HID, 8>), dim3(N_NODES / 8), dim3(HID), 0, stream,
                           h, cWr_l, cbr_l, xr, N_NODES, HID);
        hipLaunchKernelGGL(init_mx_den_kernel, dim3((N_NODES * HEADS + 255) / 256), dim3(256), 0,
                           stream, mx, den);
        if (use_ea) {
            hipLaunchKernelGGL((att_logit6_kernel<8>), dim3(EF / 8), dim3(HID), 0, stream,
                               ea, loop_attr, cWe_l, catt_l, xl, xr, ei_src, ei_dst, logit, mx);
        } else {
            hipLaunchKernelGGL((att_logit5_kernel<8>), dim3(EF / 8), dim3(HID), 0, stream,
                               edge_attr, eW, eb, eg, ebe, loop_attr,
                               cWe_l, catt_l, xl, xr, ei_src, ei_dst, logit, mx);
        }
        hipLaunchKernelGGL(softmax_norm_kernel,
                           dim3((int)(((long)EF * HEADS + 255) / 256)), dim3(256), 0, stream,
                           ei_dst, mx, logit, den);
        hipLaunchKernelGGL(zero_kernel, dim3(1024), dim3(256), 0, stream,
                           aggout, (long)N_NODES * HID);
        hipLaunchKernelGGL(aggregate_kernel,
                           dim3((int)(((long)EF * HID + 255) / 256)), dim3(256), 0, stream,
                           logit, den, xl, ei_src, ei_dst, aggout);
        hipLaunchKernelGGL(residual_kernel, dim3((N_NODES * HID + 255) / 256), dim3(256), 0, stream,
                           aggout, cbias_l, h);
    }

    // 6. noise head
    hipLaunchKernelGGL((gemm_kernel<HID, 8>), dim3(N_NODES / 8), dim3(HID), 0, stream,
                       h, nW1, nb1, tmp1, N_NODES, HID);
    hipLaunchKernelGGL(ln_gelu_kernel, dim3(N_NODES), dim3(HID), 0, stream,
                       tmp1, ng, nbe, (const float*)nullptr, (const int*)nullptr);
    hipLaunchKernelGGL((gemm_kernel<NODE_OUT, 8>), dim3(N_NODES / 8), dim3(NODE_OUT), 0, stream,
                       tmp1, nW2, nb2, pred_noise, N_NODES, HID);

    // 7. pooling + props head
    hipLaunchKernelGGL(zero_kernel, dim3(4), dim3(256), 0, stream,
                       gsum, (long)N_GRAPHS * HID);
    hipLaunchKernelGGL(zero_kernel, dim3(1), dim3(64), 0, stream, gcnt, (long)N_GRAPHS);
    hipLaunchKernelGGL(pool_kernel, dim3((N_NODES + POOL_NODES - 1) / POOL_NODES), dim3(HID), 0,
                       stream, h, batch, gsum, gcnt);
    hipLaunchKernelGGL(props_kernel, dim3(N_GRAPHS), dim3(HID), 0, stream,
                       gsum, gcnt, pW1, pb1, pg, pbe, pW2, pb2, pred_props);
}

// Round 7
// 3681.933 us; speedup vs baseline: 1.7106x; 1.1640x over previous
//
#include <hip/hip_runtime.h>
#include <hip/hip_fp16.h>
#include <math.h>

#define N_NODES 30000
#define N_EDGES 480000
#define N_GRAPHS 16
#define HID 128
#define HEADS 8
#define HEAD_DIM 16
#define NODE_IN 64
#define EDGE_IN 32
#define COND 8
#define NODE_OUT 64
#define NLAYERS 4
#define EF (N_EDGES + N_NODES) /* 510000 */
#define LN_EPS 1e-5f

__device__ __forceinline__ float gelu_f(float x) {
    return 0.5f * x * (1.0f + erff(x * 0.70710678118654752440f));
}

__device__ __forceinline__ void atomicMaxF(float* addr, float val) {
    if (val >= 0.0f) {
        atomicMax((int*)addr, __float_as_int(val));
    } else {
        atomicMin((unsigned int*)addr, __float_as_uint(val));
    }
}

// ---------- generic zero ----------
__global__ void zero_kernel(float* __restrict__ p, long n) {
    long i = (long)blockIdx.x * blockDim.x + threadIdx.x;
    long stride = (long)gridDim.x * blockDim.x;
    for (; i < n; i += stride) p[i] = 0.0f;
}

// ---------- time MLP: t[16] -> t_emb[16,128] ----------
__global__ void time_mlp_kernel(const float* __restrict__ t,
                                const float* __restrict__ tW1, const float* __restrict__ tb1,
                                const float* __restrict__ tW2, const float* __restrict__ tb2,
                                float* __restrict__ t_emb) {
    __shared__ float hsh[HID];
    int b = blockIdx.x, j = threadIdx.x;
    float tv = t[b];
    hsh[j] = gelu_f(tv * tW1[j] + tb1[j]);
    __syncthreads();
    float acc = tb2[j];
    for (int k = 0; k < HID; ++k) acc += hsh[k] * tW2[k * HID + j];
    t_emb[b * HID + j] = acc;
}

// ---------- concat x(64) + conditions[batch](8) -> xc[N,72] ----------
__global__ void concat_kernel(const float* __restrict__ x, const float* __restrict__ cond,
                              const int* __restrict__ batch, float* __restrict__ xc) {
    int idx = blockIdx.x * blockDim.x + threadIdx.x;
    if (idx >= N_NODES * 72) return;
    int n = idx / 72, c = idx % 72;
    xc[idx] = (c < NODE_IN) ? x[n * NODE_IN + c] : cond[batch[n] * COND + (c - NODE_IN)];
}

// ---------- generic GEMM: C[M,NCOL] = A[M,K] @ B[K,NCOL] + bias ----------
template <int NCOL, int R>
__global__ void gemm_kernel(const float* __restrict__ A, const float* __restrict__ B,
                            const float* __restrict__ bias, float* __restrict__ C,
                            int M, int K) {
    __shared__ __align__(16) float sh[R * HID];
    int j = threadIdx.x;
    int row0 = blockIdx.x * R;
    int total = R * K;
    for (int i = j; i < total; i += NCOL) {
        int r = i / K, k = i - r * K;
        int row = row0 + r;
        sh[r * K + k] = (row < M) ? A[(long)row * K + k] : 0.0f;
    }
    __syncthreads();
    float acc[R];
    float bv = bias ? bias[j] : 0.0f;
#pragma unroll
    for (int r = 0; r < R; ++r) acc[r] = bv;
    int KB = K >> 2;
    for (int kb = 0; kb < KB; ++kb) {
        float w0 = B[(kb * 4 + 0) * NCOL + j];
        float w1 = B[(kb * 4 + 1) * NCOL + j];
        float w2 = B[(kb * 4 + 2) * NCOL + j];
        float w3 = B[(kb * 4 + 3) * NCOL + j];
#pragma unroll
        for (int r = 0; r < R; ++r) {
            float4 a = *(const float4*)&sh[r * K + kb * 4];
            acc[r] += a.x * w0 + a.y * w1 + a.z * w2 + a.w * w3;
        }
    }
#pragma unroll
    for (int r = 0; r < R; ++r) {
        int row = row0 + r;
        if (row < M) C[(long)row * NCOL + j] = acc[r];
    }
}

// ---------- in-place LayerNorm + GELU (+ optional t_emb[batch[row]]) ----------
__global__ void ln_gelu_kernel(float* __restrict__ X, const float* __restrict__ g,
                               const float* __restrict__ bta,
                               const float* __restrict__ t_emb, const int* __restrict__ batch) {
    int row = blockIdx.x, j = threadIdx.x;
    __shared__ float red[HID];
    float v = X[(long)row * HID + j];
    red[j] = v;
    __syncthreads();
    for (int s = 64; s > 0; s >>= 1) { if (j < s) red[j] += red[j + s]; __syncthreads(); }
    float mean = red[0] * (1.0f / HID);
    __syncthreads();
    float d = v - mean;
    red[j] = d * d;
    __syncthreads();
    for (int s = 64; s > 0; s >>= 1) { if (j < s) red[j] += red[j + s]; __syncthreads(); }
    float var = red[0] * (1.0f / HID);
    float y = gelu_f(d * rsqrtf(var + LN_EPS) * g[j] + bta[j]);
    if (t_emb) y += t_emb[batch[row] * HID + j];
    X[(long)row * HID + j] = y;
}

// ---------- fused: edge-encode + segment-sum into loop_sum/cnt (+ LN stats, + optional ea) ----
// MODE: 0 = stats only, 1 = +fp16 ea, 2 = +fp32 ea
template <int R, int MODE>
__global__ void edge_enc_loop_kernel(const float* __restrict__ edge_attr,
                                     const float* __restrict__ eW, const float* __restrict__ eb,
                                     const float* __restrict__ eg, const float* __restrict__ ebe,
                                     const int* __restrict__ ei_dst,
                                     float* __restrict__ loop_sum, float* __restrict__ cnt,
                                     float* __restrict__ stat,   /* [N_EDGES,2] mean,rstd */
                                     float* __restrict__ ea32, __half* __restrict__ ea16) {
    __shared__ float red[R * HID];
    __shared__ __align__(16) float sattr[R * EDGE_IN];
    __shared__ int sdst[R];
    int j = threadIdx.x;
    long e0 = (long)blockIdx.x * R;
    if (j < R * EDGE_IN / 4)
        ((float4*)sattr)[j] = ((const float4*)(edge_attr + e0 * EDGE_IN))[j];
    if (j < R) sdst[j] = ei_dst[e0 + j];
    __syncthreads();
    float val[R];
    float ebv = eb[j];
#pragma unroll
    for (int r = 0; r < R; ++r) val[r] = ebv;
#pragma unroll
    for (int kb = 0; kb < EDGE_IN / 4; ++kb) {
        float w0 = eW[(kb * 4 + 0) * HID + j];
        float w1 = eW[(kb * 4 + 1) * HID + j];
        float w2 = eW[(kb * 4 + 2) * HID + j];
        float w3 = eW[(kb * 4 + 3) * HID + j];
#pragma unroll
        for (int r = 0; r < R; ++r) {
            float4 a = *(const float4*)&sattr[r * EDGE_IN + kb * 4];
            val[r] += a.x * w0 + a.y * w1 + a.z * w2 + a.w * w3;
        }
    }
#pragma unroll
    for (int r = 0; r < R; ++r) red[r * HID + j] = val[r];
    __syncthreads();
    for (int s = 64; s > 0; s >>= 1) {
        if (j < s) {
#pragma unroll
            for (int r = 0; r < R; ++r) red[r * HID + j] += red[r * HID + j + s];
        }
        __syncthreads();
    }
    float mean[R];
#pragma unroll
    for (int r = 0; r < R; ++r) mean[r] = red[r * HID] * (1.0f / HID);
    __syncthreads();
#pragma unroll
    for (int r = 0; r < R; ++r) { float d = val[r] - mean[r]; red[r * HID + j] = d * d; }
    __syncthreads();
    for (int s = 64; s > 0; s >>= 1) {
        if (j < s) {
#pragma unroll
            for (int r = 0; r < R; ++r) red[r * HID + j] += red[r * HID + j + s];
        }
        __syncthreads();
    }
    float egv = eg[j], bev = ebe[j];
#pragma unroll
    for (int r = 0; r < R; ++r) {
        float var = red[r * HID] * (1.0f / HID);
        float rstd = rsqrtf(var + LN_EPS);
        float y = gelu_f((val[r] - mean[r]) * rstd * egv + bev);
        int d = sdst[r];
        long e = e0 + r;
        if (j == 0) { stat[e * 2] = mean[r]; stat[e * 2 + 1] = rstd; }
        if (MODE == 2) ea32[e * HID + j] = y;
        if (MODE == 1) ea16[e * HID + j] = __float2half(y);
        atomicAdd(&loop_sum[(long)d * HID + j], y);
        if (j == 0) atomicAdd(&cnt[d], 1.0f);
    }
}

__global__ void loop_div_kernel(float* __restrict__ loop_attr, const float* __restrict__ cnt) {
    int idx = blockIdx.x * blockDim.x + threadIdx.x;
    if (idx >= N_NODES * HID) return;
    int n = idx >> 7;
    loop_attr[idx] = loop_attr[idx] / fmaxf(cnt[n], 1.0f);
}

// ---------- init mx=-inf, den=0 ----------
__global__ void init_mx_den_kernel(float* __restrict__ mx, float* __restrict__ den) {
    int idx = blockIdx.x * blockDim.x + threadIdx.x;
    if (idx >= N_NODES * HEADS) return;
    mx[idx] = -INFINITY;
    den[idx] = 0.0f;
}

// ---------- shared epilogue: em GEMM + logit + atomicMax (sh[] already filled) ----------
template <int R>
__device__ __forceinline__ void em_logit_body(
        const float* __restrict__ sh, const int* __restrict__ ssrc, const int* __restrict__ sdst,
        const float* __restrict__ cWe_l, const float* __restrict__ catt_l,
        const float* __restrict__ xl, const float* __restrict__ xr,
        float* __restrict__ logit, float* __restrict__ mx, long e0, int j) {
    float acc[R];
#pragma unroll
    for (int r = 0; r < R; ++r) acc[r] = 0.0f;
    for (int kb = 0; kb < HID / 4; ++kb) {
        float w0 = cWe_l[(kb * 4 + 0) * HID + j];
        float w1 = cWe_l[(kb * 4 + 1) * HID + j];
        float w2 = cWe_l[(kb * 4 + 2) * HID + j];
        float w3 = cWe_l[(kb * 4 + 3) * HID + j];
#pragma unroll
        for (int r = 0; r < R; ++r) {
            float4 a = *(const float4*)&sh[r * HID + kb * 4];
            acc[r] += a.x * w0 + a.y * w1 + a.z * w2 + a.w * w3;
        }
    }
    float cj = catt_l[j];
    int head = j >> 4;
#pragma unroll
    for (int r = 0; r < R; ++r) {
        long e = e0 + r;
        int s = ssrc[r], d = sdst[r];
        float m = xl[(long)s * HID + j] + xr[(long)d * HID + j] + acc[r];
        m = (m > 0.0f) ? m : 0.2f * m;
        float p = m * cj;
        p += __shfl_down(p, 8, 16);
        p += __shfl_down(p, 4, 16);
        p += __shfl_down(p, 2, 16);
        p += __shfl_down(p, 1, 16);
        if ((j & 15) == 0) {
            logit[e * HEADS + head] = p;
            atomicMaxF(&mx[(long)d * HEADS + head], p);
        }
    }
}

// ---------- att kernel, mode 0: re-encode with CACHED LN stats (no LDS tree) ----------
template <int R>
__global__ void att_logit7_kernel(const float* __restrict__ edge_attr,
                                  const float* __restrict__ eW, const float* __restrict__ eb,
                                  const float* __restrict__ eg, const float* __restrict__ ebe,
                                  const float* __restrict__ stat,   /* [N_EDGES,2] */
                                  const float* __restrict__ loop_attr,
                                  const float* __restrict__ cWe_l, const float* __restrict__ catt_l,
                                  const float* __restrict__ xl, const float* __restrict__ xr,
                                  const int* __restrict__ ei_src, const int* __restrict__ ei_dst,
                                  float* __restrict__ logit, float* __restrict__ mx) {
    __shared__ __align__(16) float sh[R * HID];
    __shared__ __align__(16) float sattr[R * EDGE_IN];
    __shared__ float sstat[R * 2];
    __shared__ int ssrc[R], sdst[R];
    int j = threadIdx.x;
    long e0 = (long)blockIdx.x * R;
    bool realblk = (e0 < N_EDGES);

    if (realblk) {
        if (j < R * EDGE_IN / 4)
            ((float4*)sattr)[j] = ((const float4*)(edge_attr + e0 * EDGE_IN))[j];
        if (j < R * 2) sstat[j] = stat[e0 * 2 + j];
        if (j < R) { ssrc[j] = ei_src[e0 + j]; sdst[j] = ei_dst[e0 + j]; }
    } else {
        if (j < R) ssrc[j] = sdst[j] = (int)(e0 + j - N_EDGES);
    }
    __syncthreads();

    if (realblk) {
        float val[R];
        float ebv = eb[j];
#pragma unroll
        for (int r = 0; r < R; ++r) val[r] = ebv;
#pragma unroll
        for (int kb = 0; kb < EDGE_IN / 4; ++kb) {
            float w0 = eW[(kb * 4 + 0) * HID + j];
            float w1 = eW[(kb * 4 + 1) * HID + j];
            float w2 = eW[(kb * 4 + 2) * HID + j];
            float w3 = eW[(kb * 4 + 3) * HID + j];
#pragma unroll
            for (int r = 0; r < R; ++r) {
                float4 a = *(const float4*)&sattr[r * EDGE_IN + kb * 4];
                val[r] += a.x * w0 + a.y * w1 + a.z * w2 + a.w * w3;
            }
        }
        float egv = eg[j], bev = ebe[j];
#pragma unroll
        for (int r = 0; r < R; ++r) {
            float mean = sstat[r * 2], rstd = sstat[r * 2 + 1];
            sh[r * HID + j] = gelu_f((val[r] - mean) * rstd * egv + bev);
        }
    } else {
#pragma unroll
        for (int r = 0; r < R; ++r)
            sh[r * HID + j] = loop_attr[(long)(e0 + r - N_EDGES) * HID + j];
    }
    __syncthreads();
    em_logit_body<R>(sh, ssrc, sdst, cWe_l, catt_l, xl, xr, logit, mx, e0, j);
}

// ---------- att kernel, mode 2: stream precomputed fp32 ea ----------
template <int R>
__global__ void att_logit6_kernel(const float* __restrict__ ea,
                                  const float* __restrict__ loop_attr,
                                  const float* __restrict__ cWe_l, const float* __restrict__ catt_l,
                                  const float* __restrict__ xl, const float* __restrict__ xr,
                                  const int* __restrict__ ei_src, const int* __restrict__ ei_dst,
                                  float* __restrict__ logit, float* __restrict__ mx) {
    __shared__ __align__(16) float sh[R * HID];
    __shared__ int ssrc[R], sdst[R];
    int j = threadIdx.x;
    long e0 = (long)blockIdx.x * R;
    bool realblk = (e0 < N_EDGES);
    const float* srcp = realblk ? (ea + e0 * HID) : (loop_attr + (e0 - N_EDGES) * HID);
    const float4* s4 = (const float4*)srcp;
    ((float4*)sh)[j]       = s4[j];
    ((float4*)sh)[j + HID] = s4[j + HID];
    if (j < R) {
        long e = e0 + j;
        if (realblk) { ssrc[j] = ei_src[e]; sdst[j] = ei_dst[e]; }
        else         { ssrc[j] = sdst[j] = (int)(e - N_EDGES); }
    }
    __syncthreads();
    em_logit_body<R>(sh, ssrc, sdst, cWe_l, catt_l, xl, xr, logit, mx, e0, j);
}

// ---------- att kernel, mode 1: stream precomputed fp16 ea ----------
template <int R>
__global__ void att_logit6h_kernel(const __half* __restrict__ ea,
                                   const float* __restrict__ loop_attr,
                                   const float* __restrict__ cWe_l, const float* __restrict__ catt_l,
                                   const float* __restrict__ xl, const float* __restrict__ xr,
                                   const int* __restrict__ ei_src, const int* __restrict__ ei_dst,
                                   float* __restrict__ logit, float* __restrict__ mx) {
    __shared__ __align__(16) float sh[R * HID];
    __shared__ int ssrc[R], sdst[R];
    int j = threadIdx.x;
    long e0 = (long)blockIdx.x * R;
    bool realblk = (e0 < N_EDGES);
    if (realblk) {
        const __half2* s2 = (const __half2*)(ea + e0 * HID);
        __half2 a0 = s2[2 * j], a1 = s2[2 * j + 1];
        float2 f0 = __half22float2(a0), f1 = __half22float2(a1);
        ((float4*)sh)[j] = make_float4(f0.x, f0.y, f1.x, f1.y);
        a0 = s2[2 * (j + HID)]; a1 = s2[2 * (j + HID) + 1];
        f0 = __half22float2(a0); f1 = __half22float2(a1);
        ((float4*)sh)[j + HID] = make_float4(f0.x, f0.y, f1.x, f1.y);
    } else {
        const float4* s4 = (const float4*)(loop_attr + (e0 - N_EDGES) * HID);
        ((float4*)sh)[j]       = s4[j];
        ((float4*)sh)[j + HID] = s4[j + HID];
    }
    if (j < R) {
        long e = e0 + j;
        if (realblk) { ssrc[j] = ei_src[e]; sdst[j] = ei_dst[e]; }
        else         { ssrc[j] = sdst[j] = (int)(e - N_EDGES); }
    }
    __syncthreads();
    em_logit_body<R>(sh, ssrc, sdst, cWe_l, catt_l, xl, xr, logit, mx, e0, j);
}

// ---------- exp(logit-mx), accumulate denominator ----------
__global__ void softmax_norm_kernel(const int* __restrict__ ei_dst, const float* __restrict__ mx,
                                    float* __restrict__ logit, float* __restrict__ den) {
    long idx = (long)blockIdx.x * blockDim.x + threadIdx.x;
    if (idx >= (long)EF * HEADS) return;
    long e = idx >> 3;
    int hh = (int)(idx & 7);
    int d = (e < N_EDGES) ? ei_dst[e] : (int)(e - N_EDGES);
    float ex = expf(logit[idx] - mx[(long)d * HEADS + hh]);
    logit[idx] = ex;
    atomicAdd(&den[(long)d * HEADS + hh], ex);
}

// ---------- alpha-weighted aggregation ----------
__global__ void aggregate_kernel(const float* __restrict__ logit, const float* __restrict__ den,
                                 const float* __restrict__ xl,
                                 const int* __restrict__ ei_src, const int* __restrict__ ei_dst,
                                 float* __restrict__ aggout) {
    long idx = (long)blockIdx.x * blockDim.x + threadIdx.x;
    if (idx >= (long)EF * HID) return;
    long e = idx >> 7;
    int j = (int)(idx & 127);
    int s, d;
    if (e < N_EDGES) { s = ei_src[e]; d = ei_dst[e]; }
    else             { s = d = (int)(e - N_EDGES); }
    int head = j >> 4;
    float alpha = logit[e * HEADS + head] / (den[(long)d * HEADS + head] + 1e-16f);
    atomicAdd(&aggout[(long)d * HID + j], alpha * xl[(long)s * HID + j]);
}

// ---------- h = gelu(aggout + cbias) + h ----------
__global__ void residual_kernel(const float* __restrict__ aggout, const float* __restrict__ cbias_l,
                                float* __restrict__ h) {
    int idx = blockIdx.x * blockDim.x + threadIdx.x;
    if (idx >= N_NODES * HID) return;
    int j = idx & 127;
    h[idx] = gelu_f(aggout[idx] + cbias_l[j]) + h[idx];
}

// ---------- pooling ----------
#define POOL_NODES 64
__global__ void pool_kernel(const float* __restrict__ h, const int* __restrict__ batch,
                            float* __restrict__ gsum, float* __restrict__ gcnt) {
    __shared__ float acc[N_GRAPHS][HID];
    __shared__ float cnt_sh[N_GRAPHS];
    int j = threadIdx.x;
    for (int g = 0; g < N_GRAPHS; ++g) acc[g][j] = 0.0f;
    if (j < N_GRAPHS) cnt_sh[j] = 0.0f;
    __syncthreads();
    int n0 = blockIdx.x * POOL_NODES;
    for (int i = 0; i < POOL_NODES; ++i) {
        int n = n0 + i;
        if (n >= N_NODES) break;
        int g = batch[n];
        acc[g][j] += h[(long)n * HID + j];
        if (j == 0) cnt_sh[g] += 1.0f;
    }
    __syncthreads();
    for (int g = 0; g < N_GRAPHS; ++g) atomicAdd(&gsum[g * HID + j], acc[g][j]);
    if (j < N_GRAPHS) atomicAdd(&gcnt[j], cnt_sh[j]);
}

// ---------- props head ----------
__global__ void props_kernel(const float* __restrict__ gsum, const float* __restrict__ gcnt,
                             const float* __restrict__ pW1, const float* __restrict__ pb1,
                             const float* __restrict__ pg, const float* __restrict__ pbe,
                             const float* __restrict__ pW2, const float* __restrict__ pb2,
                             float* __restrict__ out_props) {
    int g = blockIdx.x, j = threadIdx.x;
    __shared__ float feat[HID], red[HID], t2[HID];
    float c = fmaxf(gcnt[g], 1.0f);
    feat[j] = gsum[g * HID + j] / c;
    __syncthreads();
    float acc = pb1[j];
    for (int k = 0; k < HID; ++k) acc += feat[k] * pW1[k * HID + j];
    red[j] = acc;
    __syncthreads();
    for (int s = 64; s > 0; s >>= 1) { if (j < s) red[j] += red[j + s]; __syncthreads(); }
    float mean = red[0] * (1.0f / HID);
    __syncthreads();
    float dd = acc - mean;
    red[j] = dd * dd;
    __syncthreads();
    for (int s = 64; s > 0; s >>= 1) { if (j < s) red[j] += red[j + s]; __syncthreads(); }
    float var = red[0] * (1.0f / HID);
    t2[j] = gelu_f(dd * rsqrtf(var + LN_EPS) * pg[j] + pbe[j]);
    __syncthreads();
    if (j < COND) {
        float a = pb2[j];
        for (int k = 0; k < HID; ++k) a += t2[k] * pW2[k * COND + j];
        out_props[g * COND + j] = a;
    }
}

extern "C" void kernel_launch(void* const* d_in, const int* in_sizes, int n_in,
                              void* d_out, int out_size, void* d_ws, size_t ws_size,
                              hipStream_t stream) {
    const float* x        = (const float*)d_in[0];
    const float* edge_attr= (const float*)d_in[1];
    const float* t        = (const float*)d_in[2];
    const float* conds    = (const float*)d_in[3];
    const float* tW1      = (const float*)d_in[4];
    const float* tb1      = (const float*)d_in[5];
    const float* tW2      = (const float*)d_in[6];
    const float* tb2      = (const float*)d_in[7];
    const float* encW     = (const float*)d_in[8];
    const float* encb     = (const float*)d_in[9];
    const float* encg     = (const float*)d_in[10];
    const float* encbe    = (const float*)d_in[11];
    const float* eW       = (const float*)d_in[12];
    const float* eb       = (const float*)d_in[13];
    const float* eg       = (const float*)d_in[14];
    const float* ebe      = (const float*)d_in[15];
    const float* cWl      = (const float*)d_in[16];
    const float* cbl      = (const float*)d_in[17];
    const float* cWr      = (const float*)d_in[18];
    const float* cbr      = (const float*)d_in[19];
    const float* cWe      = (const float*)d_in[20];
    const float* catt     = (const float*)d_in[21];
    const float* cbias    = (const float*)d_in[22];
    const float* nW1      = (const float*)d_in[23];
    const float* nb1      = (const float*)d_in[24];
    const float* ng       = (const float*)d_in[25];
    const float* nbe      = (const float*)d_in[26];
    const float* nW2      = (const float*)d_in[27];
    const float* nb2      = (const float*)d_in[28];
    const float* pW1      = (const float*)d_in[29];
    const float* pb1      = (const float*)d_in[30];
    const float* pg       = (const float*)d_in[31];
    const float* pbe      = (const float*)d_in[32];
    const float* pW2      = (const float*)d_in[33];
    const float* pb2      = (const float*)d_in[34];
    const int* edge_index = (const int*)d_in[35];
    const int* batch      = (const int*)d_in[36];
    const int* ei_src = edge_index;
    const int* ei_dst = edge_index + N_EDGES;

    // workspace layout (base ~98.5 MB of f32; + ea if it fits: fp32 246 MB / fp16 123 MB)
    float* ws = (float*)d_ws;
    size_t off = 0;
    auto alloc = [&](size_t n) { float* p = ws + off; off += n; return p; };
    float* t_emb     = alloc((size_t)N_GRAPHS * HID);
    float* h         = alloc((size_t)N_NODES * HID);
    float* loop_attr = alloc((size_t)N_NODES * HID);
    float* cnt       = alloc((size_t)N_NODES);
    float* xl        = alloc((size_t)N_NODES * HID);
    float* xr        = alloc((size_t)N_NODES * HID);
    float* logit     = alloc((size_t)EF * HEADS);      // 4.08M floats
    float* mx        = alloc((size_t)N_NODES * HEADS);
    float* den       = alloc((size_t)N_NODES * HEADS);
    float* aggout    = alloc((size_t)N_NODES * HID);
    float* gsum      = alloc((size_t)N_GRAPHS * HID);
    float* gcnt      = alloc((size_t)N_GRAPHS);
    float* stat      = alloc((size_t)N_EDGES * 2);     // mean,rstd per edge (3.84 MB)
    size_t base_bytes = off * sizeof(float);
    float*  ea32 = ws + off;
    __half* ea16 = (__half*)(ws + off);
    int mode = 0;
    if (ws_size >= base_bytes + (size_t)N_EDGES * HID * sizeof(float)) mode = 2;
    else if (ws_size >= base_bytes + (size_t)N_EDGES * HID * sizeof(__half)) mode = 1;
    // aliases (disjoint lifetimes):
    float* xc   = logit;  // [N,72] = 2.16M floats, used only pre-layers; logit is 4.08M
    float* tmp1 = xl;     // used only post-layers
    (void)in_sizes; (void)n_in; (void)out_size;

    float* pred_noise = (float*)d_out;                              // [N,64]
    float* pred_props = (float*)d_out + (size_t)N_NODES * NODE_OUT; // [16,8]

    // 1. time MLP
    hipLaunchKernelGGL(time_mlp_kernel, dim3(N_GRAPHS), dim3(HID), 0, stream,
                       t, tW1, tb1, tW2, tb2, t_emb);
    // 2. concat
    hipLaunchKernelGGL(concat_kernel, dim3((N_NODES * 72 + 255) / 256), dim3(256), 0, stream,
                       x, conds, batch, xc);
    // 3. node encoder gemm + LN/GELU (+t_emb[batch])
    hipLaunchKernelGGL((gemm_kernel<HID, 8>), dim3(N_NODES / 8), dim3(HID), 0, stream,
                       xc, encW, encb, h, N_NODES, 72);
    hipLaunchKernelGGL(ln_gelu_kernel, dim3(N_NODES), dim3(HID), 0, stream,
                       h, encg, encbe, t_emb, batch);
    // 4. edge encode (stats always; ea memoized per mode) + self-loop segment-mean
    hipLaunchKernelGGL(zero_kernel, dim3(1024), dim3(256), 0, stream,
                       loop_attr, (long)N_NODES * HID);
    hipLaunchKernelGGL(zero_kernel, dim3(64), dim3(256), 0, stream, cnt, (long)N_NODES);
    if (mode == 2) {
        hipLaunchKernelGGL((edge_enc_loop_kernel<8, 2>), dim3(N_EDGES / 8), dim3(HID), 0, stream,
                           edge_attr, eW, eb, eg, ebe, ei_dst, loop_attr, cnt, stat, ea32, ea16);
    } else if (mode == 1) {
        hipLaunchKernelGGL((edge_enc_loop_kernel<8, 1>), dim3(N_EDGES / 8), dim3(HID), 0, stream,
                           edge_attr, eW, eb, eg, ebe, ei_dst, loop_attr, cnt, stat, ea32, ea16);
    } else {
        hipLaunchKernelGGL((edge_enc_loop_kernel<8, 0>), dim3(N_EDGES / 8), dim3(HID), 0, stream,
                           edge_attr, eW, eb, eg, ebe, ei_dst, loop_attr, cnt, stat, ea32, ea16);
    }
    hipLaunchKernelGGL(loop_div_kernel, dim3((N_NODES * HID + 255) / 256), dim3(256), 0, stream,
                       loop_attr, cnt);

    // 5. layers
    for (int l = 0; l < NLAYERS; ++l) {
        const float* cWl_l = cWl + (size_t)l * HID * HID;
        const float* cWr_l = cWr + (size_t)l * HID * HID;
        const float* cWe_l = cWe + (size_t)l * HID * HID;
        const float* cbl_l = cbl + (size_t)l * HID;
        const float* cbr_l = cbr + (size_t)l * HID;
        const float* catt_l = catt + (size_t)l * HID;
        const float* cbias_l = cbias + (size_t)l * HID;

        hipLaunchKernelGGL((gemm_kernel<HID, 8>), dim3(N_NODES / 8), dim3(HID), 0, stream,
                           h, cWl_l, cbl_l, xl, N_NODES, HID);
        hipLaunchKernelGGL((gemm_kernel<HID, 8>), dim3(N_NODES / 8), dim3(HID), 0, stream,
                           h, cWr_l, cbr_l, xr, N_NODES, HID);
        hipLaunchKernelGGL(init_mx_den_kernel, dim3((N_NODES * HEADS + 255) / 256), dim3(256), 0,
                           stream, mx, den);
        if (mode == 2) {
            hipLaunchKernelGGL((att_logit6_kernel<8>), dim3(EF / 8), dim3(HID), 0, stream,
                               ea32, loop_attr, cWe_l, catt_l, xl, xr, ei_src, ei_dst, logit, mx);
        } else if (mode == 1) {
            hipLaunchKernelGGL((att_logit6h_kernel<8>), dim3(EF / 8), dim3(HID), 0, stream,
                               ea16, loop_attr, cWe_l, catt_l, xl, xr, ei_src, ei_dst, logit, mx);
        } else {
            hipLaunchKernelGGL((att_logit7_kernel<8>), dim3(EF / 8), dim3(HID), 0, stream,
                               edge_attr, eW, eb, eg, ebe, stat, loop_attr,
                               cWe_l, catt_l, xl, xr, ei_src, ei_dst, logit, mx);
        }
        hipLaunchKernelGGL(softmax_norm_kernel,
                           dim3((int)(((long)EF * HEADS + 255) / 256)), dim3(256), 0, stream,
                           ei_dst, mx, logit, den);
        hipLaunchKernelGGL(zero_kernel, dim3(1024), dim3(256), 0, stream,
                           aggout, (long)N_NODES * HID);
        hipLaunchKernelGGL(aggregate_kernel,
                           dim3((int)(((long)EF * HID + 255) / 256)), dim3(256), 0, stream,
                           logit, den, xl, ei_src, ei_dst, aggout);
        hipLaunchKernelGGL(residual_kernel, dim3((N_NODES * HID + 255) / 256), dim3(256), 0, stream,
                           aggout, cbias_l, h);
    }

    // 6. noise head
    hipLaunchKernelGGL((gemm_kernel<HID, 8>), dim3(N_NODES / 8), dim3(HID), 0, stream,
                       h, nW1, nb1, tmp1, N_NODES, HID);
    hipLaunchKernelGGL(ln_gelu_kernel, dim3(N_NODES), dim3(HID), 0, stream,
                       tmp1, ng, nbe, (const float*)nullptr, (const int*)nullptr);
    hipLaunchKernelGGL((gemm_kernel<NODE_OUT, 8>), dim3(N_NODES / 8), dim3(NODE_OUT), 0, stream,
                       tmp1, nW2, nb2, pred_noise, N_NODES, HID);

    // 7. pooling + props head
    hipLaunchKernelGGL(zero_kernel, dim3(4), dim3(256), 0, stream,
                       gsum, (long)N_GRAPHS * HID);
    hipLaunchKernelGGL(zero_kernel, dim3(1), dim3(64), 0, stream, gcnt, (long)N_GRAPHS);
    hipLaunchKernelGGL(pool_kernel, dim3((N_NODES + POOL_NODES - 1) / POOL_NODES), dim3(HID), 0,
                       stream, h, batch, gsum, gcnt);
    hipLaunchKernelGGL(props_kernel, dim3(N_GRAPHS), dim3(HID), 0, stream,
                       gsum, gcnt, pW1, pb1, pg, pbe, pW2, pb2, pred_props);
}

// Round 8
// 3258.977 us; speedup vs baseline: 1.9326x; 1.1298x over previous
//
#include <hip/hip_runtime.h>
#include <hip/hip_fp16.h>
#include <math.h>

#define N_NODES 30000
#define N_EDGES 480000
#define N_GRAPHS 16
#define HID 128
#define HEADS 8
#define HEAD_DIM 16
#define NODE_IN 64
#define EDGE_IN 32
#define COND 8
#define NODE_OUT 64
#define NLAYERS 4
#define EF (N_EDGES + N_NODES) /* 510000 */
#define LN_EPS 1e-5f

__device__ __forceinline__ float gelu_f(float x) {
    return 0.5f * x * (1.0f + erff(x * 0.70710678118654752440f));
}

__device__ __forceinline__ void atomicMaxF(float* addr, float val) {
    if (val >= 0.0f) {
        atomicMax((int*)addr, __float_as_int(val));
    } else {
        atomicMin((unsigned int*)addr, __float_as_uint(val));
    }
}

// ---------- generic zero ----------
__global__ void zero_kernel(float* __restrict__ p, long n) {
    long i = (long)blockIdx.x * blockDim.x + threadIdx.x;
    long stride = (long)gridDim.x * blockDim.x;
    for (; i < n; i += stride) p[i] = 0.0f;
}

// ---------- time MLP: t[16] -> t_emb[16,128] ----------
__global__ void time_mlp_kernel(const float* __restrict__ t,
                                const float* __restrict__ tW1, const float* __restrict__ tb1,
                                const float* __restrict__ tW2, const float* __restrict__ tb2,
                                float* __restrict__ t_emb) {
    __shared__ float hsh[HID];
    int b = blockIdx.x, j = threadIdx.x;
    float tv = t[b];
    hsh[j] = gelu_f(tv * tW1[j] + tb1[j]);
    __syncthreads();
    float acc = tb2[j];
    for (int k = 0; k < HID; ++k) acc += hsh[k] * tW2[k * HID + j];
    t_emb[b * HID + j] = acc;
}

// ---------- concat x(64) + conditions[batch](8) -> xc[N,72] ----------
__global__ void concat_kernel(const float* __restrict__ x, const float* __restrict__ cond,
                              const int* __restrict__ batch, float* __restrict__ xc) {
    int idx = blockIdx.x * blockDim.x + threadIdx.x;
    if (idx >= N_NODES * 72) return;
    int n = idx / 72, c = idx % 72;
    xc[idx] = (c < NODE_IN) ? x[n * NODE_IN + c] : cond[batch[n] * COND + (c - NODE_IN)];
}

// ---------- generic GEMM: C[M,NCOL] = A[M,K] @ B[K,NCOL] + bias ----------
template <int NCOL, int R>
__global__ void gemm_kernel(const float* __restrict__ A, const float* __restrict__ B,
                            const float* __restrict__ bias, float* __restrict__ C,
                            int M, int K) {
    __shared__ __align__(16) float sh[R * HID];
    int j = threadIdx.x;
    int row0 = blockIdx.x * R;
    int total = R * K;
    for (int i = j; i < total; i += NCOL) {
        int r = i / K, k = i - r * K;
        int row = row0 + r;
        sh[r * K + k] = (row < M) ? A[(long)row * K + k] : 0.0f;
    }
    __syncthreads();
    float acc[R];
    float bv = bias ? bias[j] : 0.0f;
#pragma unroll
    for (int r = 0; r < R; ++r) acc[r] = bv;
    int KB = K >> 2;
    for (int kb = 0; kb < KB; ++kb) {
        float w0 = B[(kb * 4 + 0) * NCOL + j];
        float w1 = B[(kb * 4 + 1) * NCOL + j];
        float w2 = B[(kb * 4 + 2) * NCOL + j];
        float w3 = B[(kb * 4 + 3) * NCOL + j];
#pragma unroll
        for (int r = 0; r < R; ++r) {
            float4 a = *(const float4*)&sh[r * K + kb * 4];
            acc[r] += a.x * w0 + a.y * w1 + a.z * w2 + a.w * w3;
        }
    }
#pragma unroll
    for (int r = 0; r < R; ++r) {
        int row = row0 + r;
        if (row < M) C[(long)row * NCOL + j] = acc[r];
    }
}

// ---------- fused dual GEMM: Cl = A@Bl + bl, Cr = A@Br + br (K = HID) ----------
// One h-staging feeds both weight matrices: halves LDS reads & A HBM traffic.
template <int R>
__global__ void gemm2_kernel(const float* __restrict__ A,
                             const float* __restrict__ Bl, const float* __restrict__ bl,
                             const float* __restrict__ Br, const float* __restrict__ br,
                             float* __restrict__ Cl, float* __restrict__ Cr, int M) {
    __shared__ __align__(16) float sh[R * HID];
    int j = threadIdx.x;
    int row0 = blockIdx.x * R;
    for (int i = j; i < R * HID; i += HID) {
        int r = i >> 7, k = i & 127;
        int row = row0 + r;
        sh[i] = (row < M) ? A[(long)row * HID + k] : 0.0f;
    }
    __syncthreads();
    float accl[R], accr[R];
    float blv = bl[j], brv = br[j];
#pragma unroll
    for (int r = 0; r < R; ++r) { accl[r] = blv; accr[r] = brv; }
    for (int kb = 0; kb < HID / 4; ++kb) {
        float l0 = Bl[(kb * 4 + 0) * HID + j];
        float l1 = Bl[(kb * 4 + 1) * HID + j];
        float l2 = Bl[(kb * 4 + 2) * HID + j];
        float l3 = Bl[(kb * 4 + 3) * HID + j];
        float r0 = Br[(kb * 4 + 0) * HID + j];
        float r1 = Br[(kb * 4 + 1) * HID + j];
        float r2 = Br[(kb * 4 + 2) * HID + j];
        float r3 = Br[(kb * 4 + 3) * HID + j];
#pragma unroll
        for (int r = 0; r < R; ++r) {
            float4 a = *(const float4*)&sh[r * HID + kb * 4];
            accl[r] += a.x * l0 + a.y * l1 + a.z * l2 + a.w * l3;
            accr[r] += a.x * r0 + a.y * r1 + a.z * r2 + a.w * r3;
        }
    }
#pragma unroll
    for (int r = 0; r < R; ++r) {
        int row = row0 + r;
        if (row < M) {
            Cl[(long)row * HID + j] = accl[r];
            Cr[(long)row * HID + j] = accr[r];
        }
    }
}

// ---------- in-place LayerNorm + GELU (+ optional t_emb[batch[row]]) ----------
__global__ void ln_gelu_kernel(float* __restrict__ X, const float* __restrict__ g,
                               const float* __restrict__ bta,
                               const float* __restrict__ t_emb, const int* __restrict__ batch) {
    int row = blockIdx.x, j = threadIdx.x;
    __shared__ float red[HID];
    float v = X[(long)row * HID + j];
    red[j] = v;
    __syncthreads();
    for (int s = 64; s > 0; s >>= 1) { if (j < s) red[j] += red[j + s]; __syncthreads(); }
    float mean = red[0] * (1.0f / HID);
    __syncthreads();
    float d = v - mean;
    red[j] = d * d;
    __syncthreads();
    for (int s = 64; s > 0; s >>= 1) { if (j < s) red[j] += red[j + s]; __syncthreads(); }
    float var = red[0] * (1.0f / HID);
    float y = gelu_f(d * rsqrtf(var + LN_EPS) * g[j] + bta[j]);
    if (t_emb) y += t_emb[batch[row] * HID + j];
    X[(long)row * HID + j] = y;
}

// ---------- fused: edge-encode + segment-sum into loop_sum/cnt (+ LN stats, + optional ea) ----
// MODE: 0 = stats only, 1 = +fp16 ea, 2 = +fp32 ea
template <int R, int MODE>
__global__ void edge_enc_loop_kernel(const float* __restrict__ edge_attr,
                                     const float* __restrict__ eW, const float* __restrict__ eb,
                                     const float* __restrict__ eg, const float* __restrict__ ebe,
                                     const int* __restrict__ ei_dst,
                                     float* __restrict__ loop_sum, float* __restrict__ cnt,
                                     float* __restrict__ stat,   /* [N_EDGES,2] mean,rstd */
                                     float* __restrict__ ea32, __half* __restrict__ ea16) {
    __shared__ float red[R * HID];
    __shared__ __align__(16) float sattr[R * EDGE_IN];
    __shared__ int sdst[R];
    int j = threadIdx.x;
    long e0 = (long)blockIdx.x * R;
    if (j < R * EDGE_IN / 4)
        ((float4*)sattr)[j] = ((const float4*)(edge_attr + e0 * EDGE_IN))[j];
    if (j < R) sdst[j] = ei_dst[e0 + j];
    __syncthreads();
    float val[R];
    float ebv = eb[j];
#pragma unroll
    for (int r = 0; r < R; ++r) val[r] = ebv;
#pragma unroll
    for (int kb = 0; kb < EDGE_IN / 4; ++kb) {
        float w0 = eW[(kb * 4 + 0) * HID + j];
        float w1 = eW[(kb * 4 + 1) * HID + j];
        float w2 = eW[(kb * 4 + 2) * HID + j];
        float w3 = eW[(kb * 4 + 3) * HID + j];
#pragma unroll
        for (int r = 0; r < R; ++r) {
            float4 a = *(const float4*)&sattr[r * EDGE_IN + kb * 4];
            val[r] += a.x * w0 + a.y * w1 + a.z * w2 + a.w * w3;
        }
    }
#pragma unroll
    for (int r = 0; r < R; ++r) red[r * HID + j] = val[r];
    __syncthreads();
    for (int s = 64; s > 0; s >>= 1) {
        if (j < s) {
#pragma unroll
            for (int r = 0; r < R; ++r) red[r * HID + j] += red[r * HID + j + s];
        }
        __syncthreads();
    }
    float mean[R];
#pragma unroll
    for (int r = 0; r < R; ++r) mean[r] = red[r * HID] * (1.0f / HID);
    __syncthreads();
#pragma unroll
    for (int r = 0; r < R; ++r) { float d = val[r] - mean[r]; red[r * HID + j] = d * d; }
    __syncthreads();
    for (int s = 64; s > 0; s >>= 1) {
        if (j < s) {
#pragma unroll
            for (int r = 0; r < R; ++r) red[r * HID + j] += red[r * HID + j + s];
        }
        __syncthreads();
    }
    float egv = eg[j], bev = ebe[j];
#pragma unroll
    for (int r = 0; r < R; ++r) {
        float var = red[r * HID] * (1.0f / HID);
        float rstd = rsqrtf(var + LN_EPS);
        float y = gelu_f((val[r] - mean[r]) * rstd * egv + bev);
        int d = sdst[r];
        long e = e0 + r;
        if (j == 0) { stat[e * 2] = mean[r]; stat[e * 2 + 1] = rstd; }
        if (MODE == 2) ea32[e * HID + j] = y;
        if (MODE == 1) ea16[e * HID + j] = __float2half(y);
        atomicAdd(&loop_sum[(long)d * HID + j], y);
        if (j == 0) atomicAdd(&cnt[d], 1.0f);
    }
}

__global__ void loop_div_kernel(float* __restrict__ loop_attr, const float* __restrict__ cnt) {
    int idx = blockIdx.x * blockDim.x + threadIdx.x;
    if (idx >= N_NODES * HID) return;
    int n = idx >> 7;
    loop_attr[idx] = loop_attr[idx] / fmaxf(cnt[n], 1.0f);
}

// ---------- init mx=-inf, den=0 ----------
__global__ void init_mx_den_kernel(float* __restrict__ mx, float* __restrict__ den) {
    int idx = blockIdx.x * blockDim.x + threadIdx.x;
    if (idx >= N_NODES * HEADS) return;
    mx[idx] = -INFINITY;
    den[idx] = 0.0f;
}

// ---------- shared epilogue (1 col/thread variants) ----------
template <int R>
__device__ __forceinline__ void em_logit_body(
        const float* __restrict__ sh, const int* __restrict__ ssrc, const int* __restrict__ sdst,
        const float* __restrict__ cWe_l, const float* __restrict__ catt_l,
        const float* __restrict__ xl, const float* __restrict__ xr,
        float* __restrict__ logit, float* __restrict__ mx, long e0, int j) {
    float acc[R];
#pragma unroll
    for (int r = 0; r < R; ++r) acc[r] = 0.0f;
    for (int kb = 0; kb < HID / 4; ++kb) {
        float w0 = cWe_l[(kb * 4 + 0) * HID + j];
        float w1 = cWe_l[(kb * 4 + 1) * HID + j];
        float w2 = cWe_l[(kb * 4 + 2) * HID + j];
        float w3 = cWe_l[(kb * 4 + 3) * HID + j];
#pragma unroll
        for (int r = 0; r < R; ++r) {
            float4 a = *(const float4*)&sh[r * HID + kb * 4];
            acc[r] += a.x * w0 + a.y * w1 + a.z * w2 + a.w * w3;
        }
    }
    float cj = catt_l[j];
    int head = j >> 4;
#pragma unroll
    for (int r = 0; r < R; ++r) {
        long e = e0 + r;
        int s = ssrc[r], d = sdst[r];
        float m = xl[(long)s * HID + j] + xr[(long)d * HID + j] + acc[r];
        m = (m > 0.0f) ? m : 0.2f * m;
        float p = m * cj;
        p += __shfl_down(p, 8, 16);
        p += __shfl_down(p, 4, 16);
        p += __shfl_down(p, 2, 16);
        p += __shfl_down(p, 1, 16);
        if ((j & 15) == 0) {
            logit[e * HEADS + head] = p;
            atomicMaxF(&mx[(long)d * HEADS + head], p);
        }
    }
}

// ---------- att kernel, mode 0 fallback: re-encode with CACHED LN stats ----------
template <int R>
__global__ void att_logit7_kernel(const float* __restrict__ edge_attr,
                                  const float* __restrict__ eW, const float* __restrict__ eb,
                                  const float* __restrict__ eg, const float* __restrict__ ebe,
                                  const float* __restrict__ stat,
                                  const float* __restrict__ loop_attr,
                                  const float* __restrict__ cWe_l, const float* __restrict__ catt_l,
                                  const float* __restrict__ xl, const float* __restrict__ xr,
                                  const int* __restrict__ ei_src, const int* __restrict__ ei_dst,
                                  float* __restrict__ logit, float* __restrict__ mx) {
    __shared__ __align__(16) float sh[R * HID];
    __shared__ __align__(16) float sattr[R * EDGE_IN];
    __shared__ float sstat[R * 2];
    __shared__ int ssrc[R], sdst[R];
    int j = threadIdx.x;
    long e0 = (long)blockIdx.x * R;
    bool realblk = (e0 < N_EDGES);

    if (realblk) {
        if (j < R * EDGE_IN / 4)
            ((float4*)sattr)[j] = ((const float4*)(edge_attr + e0 * EDGE_IN))[j];
        if (j < R * 2) sstat[j] = stat[e0 * 2 + j];
        if (j < R) { ssrc[j] = ei_src[e0 + j]; sdst[j] = ei_dst[e0 + j]; }
    } else {
        if (j < R) ssrc[j] = sdst[j] = (int)(e0 + j - N_EDGES);
    }
    __syncthreads();

    if (realblk) {
        float val[R];
        float ebv = eb[j];
#pragma unroll
        for (int r = 0; r < R; ++r) val[r] = ebv;
#pragma unroll
        for (int kb = 0; kb < EDGE_IN / 4; ++kb) {
            float w0 = eW[(kb * 4 + 0) * HID + j];
            float w1 = eW[(kb * 4 + 1) * HID + j];
            float w2 = eW[(kb * 4 + 2) * HID + j];
            float w3 = eW[(kb * 4 + 3) * HID + j];
#pragma unroll
            for (int r = 0; r < R; ++r) {
                float4 a = *(const float4*)&sattr[r * EDGE_IN + kb * 4];
                val[r] += a.x * w0 + a.y * w1 + a.z * w2 + a.w * w3;
            }
        }
        float egv = eg[j], bev = ebe[j];
#pragma unroll
        for (int r = 0; r < R; ++r) {
            float mean = sstat[r * 2], rstd = sstat[r * 2 + 1];
            sh[r * HID + j] = gelu_f((val[r] - mean) * rstd * egv + bev);
        }
    } else {
#pragma unroll
        for (int r = 0; r < R; ++r)
            sh[r * HID + j] = loop_attr[(long)(e0 + r - N_EDGES) * HID + j];
    }
    __syncthreads();
    em_logit_body<R>(sh, ssrc, sdst, cWe_l, catt_l, xl, xr, logit, mx, e0, j);
}

// ---------- att kernel, mode 2 fallback: stream fp32 ea ----------
template <int R>
__global__ void att_logit6_kernel(const float* __restrict__ ea,
                                  const float* __restrict__ loop_attr,
                                  const float* __restrict__ cWe_l, const float* __restrict__ catt_l,
                                  const float* __restrict__ xl, const float* __restrict__ xr,
                                  const int* __restrict__ ei_src, const int* __restrict__ ei_dst,
                                  float* __restrict__ logit, float* __restrict__ mx) {
    __shared__ __align__(16) float sh[R * HID];
    __shared__ int ssrc[R], sdst[R];
    int j = threadIdx.x;
    long e0 = (long)blockIdx.x * R;
    bool realblk = (e0 < N_EDGES);
    const float* srcp = realblk ? (ea + e0 * HID) : (loop_attr + (e0 - N_EDGES) * HID);
    const float4* s4 = (const float4*)srcp;
    ((float4*)sh)[j]       = s4[j];
    ((float4*)sh)[j + HID] = s4[j + HID];
    if (j < R) {
        long e = e0 + j;
        if (realblk) { ssrc[j] = ei_src[e]; sdst[j] = ei_dst[e]; }
        else         { ssrc[j] = sdst[j] = (int)(e - N_EDGES); }
    }
    __syncthreads();
    em_logit_body<R>(sh, ssrc, sdst, cWe_l, catt_l, xl, xr, logit, mx, e0, j);
}

// ---------- att kernel, mode 1 MAIN: fp16 ea stream, 16-edge tile, 2 cols/thread ----------
// Wave w (t>>6) owns rows w*8..w*8+7; lane owns cols (lane, lane+64).
// Per kb: 8 broadcast ds_read_b128 feed 64 FMAs (2x the FMA:LDS ratio of 1-col variant).
__global__ __launch_bounds__(128) void att_logit8h_kernel(
        const __half* __restrict__ ea,
        const float* __restrict__ loop_attr,
        const float* __restrict__ cWe_l, const float* __restrict__ catt_l,
        const float* __restrict__ xl, const float* __restrict__ xr,
        const int* __restrict__ ei_src, const int* __restrict__ ei_dst,
        float* __restrict__ logit, float* __restrict__ mx) {
    const int R = 16;
    __shared__ __align__(16) float sh[R * HID];
    __shared__ int ssrc[R], sdst[R];
    int t = threadIdx.x;
    long e0 = (long)blockIdx.x * R;
    bool realblk = (e0 < N_EDGES);

    // stage 16 rows into LDS
    if (realblk) {
        const uint4* s16 = (const uint4*)(ea + e0 * HID);  // 256 uint4 of fp16
#pragma unroll
        for (int i = 0; i < 2; ++i) {
            uint4 u = s16[t + i * 128];
            int base = (t + i * 128) * 8;
            const __half2* hp = (const __half2*)&u;
            float2 f0 = __half22float2(hp[0]);
            float2 f1 = __half22float2(hp[1]);
            float2 f2 = __half22float2(hp[2]);
            float2 f3 = __half22float2(hp[3]);
            *(float4*)&sh[base]     = make_float4(f0.x, f0.y, f1.x, f1.y);
            *(float4*)&sh[base + 4] = make_float4(f2.x, f2.y, f3.x, f3.y);
        }
    } else {
        const float4* s4 = (const float4*)(loop_attr + (e0 - N_EDGES) * HID);
#pragma unroll
        for (int i = 0; i < 4; ++i)
            ((float4*)sh)[t + i * 128] = s4[t + i * 128];
    }
    if (t < R) {
        long e = e0 + t;
        if (realblk) { ssrc[t] = ei_src[e]; sdst[t] = ei_dst[e]; }
        else         { ssrc[t] = sdst[t] = (int)(e - N_EDGES); }
    }
    __syncthreads();

    int lane = t & 63;
    int rb = (t >> 6) * 8;
    int j1 = lane, j2 = lane + 64;
    float acc1[8], acc2[8];
#pragma unroll
    for (int r = 0; r < 8; ++r) { acc1[r] = 0.0f; acc2[r] = 0.0f; }
    for (int kb = 0; kb < HID / 4; ++kb) {
        float w10 = cWe_l[(kb * 4 + 0) * HID + j1];
        float w11 = cWe_l[(kb * 4 + 1) * HID + j1];
        float w12 = cWe_l[(kb * 4 + 2) * HID + j1];
        float w13 = cWe_l[(kb * 4 + 3) * HID + j1];
        float w20 = cWe_l[(kb * 4 + 0) * HID + j2];
        float w21 = cWe_l[(kb * 4 + 1) * HID + j2];
        float w22 = cWe_l[(kb * 4 + 2) * HID + j2];
        float w23 = cWe_l[(kb * 4 + 3) * HID + j2];
#pragma unroll
        for (int r = 0; r < 8; ++r) {
            float4 a = *(const float4*)&sh[(rb + r) * HID + kb * 4];
            acc1[r] += a.x * w10 + a.y * w11 + a.z * w12 + a.w * w13;
            acc2[r] += a.x * w20 + a.y * w21 + a.z * w22 + a.w * w23;
        }
    }

    float c1 = catt_l[j1], c2 = catt_l[j2];
    int h1 = lane >> 4, h2 = 4 + (lane >> 4);
#pragma unroll
    for (int r = 0; r < 8; ++r) {
        int rr = rb + r;
        long e = e0 + rr;
        int s = ssrc[rr], d = sdst[rr];
        float m1 = xl[(long)s * HID + j1] + xr[(long)d * HID + j1] + acc1[r];
        m1 = (m1 > 0.0f) ? m1 : 0.2f * m1;
        float m2 = xl[(long)s * HID + j2] + xr[(long)d * HID + j2] + acc2[r];
        m2 = (m2 > 0.0f) ? m2 : 0.2f * m2;
        float p1 = m1 * c1;
        float p2 = m2 * c2;
        p1 += __shfl_down(p1, 8, 16);
        p1 += __shfl_down(p1, 4, 16);
        p1 += __shfl_down(p1, 2, 16);
        p1 += __shfl_down(p1, 1, 16);
        p2 += __shfl_down(p2, 8, 16);
        p2 += __shfl_down(p2, 4, 16);
        p2 += __shfl_down(p2, 2, 16);
        p2 += __shfl_down(p2, 1, 16);
        if ((lane & 15) == 0) {
            logit[e * HEADS + h1] = p1;
            atomicMaxF(&mx[(long)d * HEADS + h1], p1);
            logit[e * HEADS + h2] = p2;
            atomicMaxF(&mx[(long)d * HEADS + h2], p2);
        }
    }
}

// ---------- exp(logit-mx), accumulate denominator ----------
__global__ void softmax_norm_kernel(const int* __restrict__ ei_dst, const float* __restrict__ mx,
                                    float* __restrict__ logit, float* __restrict__ den) {
    long idx = (long)blockIdx.x * blockDim.x + threadIdx.x;
    if (idx >= (long)EF * HEADS) return;
    long e = idx >> 3;
    int hh = (int)(idx & 7);
    int d = (e < N_EDGES) ? ei_dst[e] : (int)(e - N_EDGES);
    float ex = expf(logit[idx] - mx[(long)d * HEADS + hh]);
    logit[idx] = ex;
    atomicAdd(&den[(long)d * HEADS + hh], ex);
}

// ---------- alpha-weighted aggregation ----------
__global__ void aggregate_kernel(const float* __restrict__ logit, const float* __restrict__ den,
                                 const float* __restrict__ xl,
                                 const int* __restrict__ ei_src, const int* __restrict__ ei_dst,
                                 float* __restrict__ aggout) {
    long idx = (long)blockIdx.x * blockDim.x + threadIdx.x;
    if (idx >= (long)EF * HID) return;
    long e = idx >> 7;
    int j = (int)(idx & 127);
    int s, d;
    if (e < N_EDGES) { s = ei_src[e]; d = ei_dst[e]; }
    else             { s = d = (int)(e - N_EDGES); }
    int head = j >> 4;
    float alpha = logit[e * HEADS + head] / (den[(long)d * HEADS + head] + 1e-16f);
    atomicAdd(&aggout[(long)d * HID + j], alpha * xl[(long)s * HID + j]);
}

// ---------- h = gelu(aggout + cbias) + h ----------
__global__ void residual_kernel(const float* __restrict__ aggout, const float* __restrict__ cbias_l,
                                float* __restrict__ h) {
    int idx = blockIdx.x * blockDim.x + threadIdx.x;
    if (idx >= N_NODES * HID) return;
    int j = idx & 127;
    h[idx] = gelu_f(aggout[idx] + cbias_l[j]) + h[idx];
}

// ---------- pooling ----------
#define POOL_NODES 64
__global__ void pool_kernel(const float* __restrict__ h, const int* __restrict__ batch,
                            float* __restrict__ gsum, float* __restrict__ gcnt) {
    __shared__ float acc[N_GRAPHS][HID];
    __shared__ float cnt_sh[N_GRAPHS];
    int j = threadIdx.x;
    for (int g = 0; g < N_GRAPHS; ++g) acc[g][j] = 0.0f;
    if (j < N_GRAPHS) cnt_sh[j] = 0.0f;
    __syncthreads();
    int n0 = blockIdx.x * POOL_NODES;
    for (int i = 0; i < POOL_NODES; ++i) {
        int n = n0 + i;
        if (n >= N_NODES) break;
        int g = batch[n];
        acc[g][j] += h[(long)n * HID + j];
        if (j == 0) cnt_sh[g] += 1.0f;
    }
    __syncthreads();
    for (int g = 0; g < N_GRAPHS; ++g) atomicAdd(&gsum[g * HID + j], acc[g][j]);
    if (j < N_GRAPHS) atomicAdd(&gcnt[j], cnt_sh[j]);
}

// ---------- props head ----------
__global__ void props_kernel(const float* __restrict__ gsum, const float* __restrict__ gcnt,
                             const float* __restrict__ pW1, const float* __restrict__ pb1,
                             const float* __restrict__ pg, const float* __restrict__ pbe,
                             const float* __restrict__ pW2, const float* __restrict__ pb2,
                             float* __restrict__ out_props) {
    int g = blockIdx.x, j = threadIdx.x;
    __shared__ float feat[HID], red[HID], t2[HID];
    float c = fmaxf(gcnt[g], 1.0f);
    feat[j] = gsum[g * HID + j] / c;
    __syncthreads();
    float acc = pb1[j];
    for (int k = 0; k < HID; ++k) acc += feat[k] * pW1[k * HID + j];
    red[j] = acc;
    __syncthreads();
    for (int s = 64; s > 0; s >>= 1) { if (j < s) red[j] += red[j + s]; __syncthreads(); }
    float mean = red[0] * (1.0f / HID);
    __syncthreads();
    float dd = acc - mean;
    red[j] = dd * dd;
    __syncthreads();
    for (int s = 64; s > 0; s >>= 1) { if (j < s) red[j] += red[j + s]; __syncthreads(); }
    float var = red[0] * (1.0f / HID);
    t2[j] = gelu_f(dd * rsqrtf(var + LN_EPS) * pg[j] + pbe[j]);
    __syncthreads();
    if (j < COND) {
        float a = pb2[j];
        for (int k = 0; k < HID; ++k) a += t2[k] * pW2[k * COND + j];
        out_props[g * COND + j] = a;
    }
}

extern "C" void kernel_launch(void* const* d_in, const int* in_sizes, int n_in,
                              void* d_out, int out_size, void* d_ws, size_t ws_size,
                              hipStream_t stream) {
    const float* x        = (const float*)d_in[0];
    const float* edge_attr= (const float*)d_in[1];
    const float* t        = (const float*)d_in[2];
    const float* conds    = (const float*)d_in[3];
    const float* tW1      = (const float*)d_in[4];
    const float* tb1      = (const float*)d_in[5];
    const float* tW2      = (const float*)d_in[6];
    const float* tb2      = (const float*)d_in[7];
    const float* encW     = (const float*)d_in[8];
    const float* encb     = (const float*)d_in[9];
    const float* encg     = (const float*)d_in[10];
    const float* encbe    = (const float*)d_in[11];
    const float* eW       = (const float*)d_in[12];
    const float* eb       = (const float*)d_in[13];
    const float* eg       = (const float*)d_in[14];
    const float* ebe      = (const float*)d_in[15];
    const float* cWl      = (const float*)d_in[16];
    const float* cbl      = (const float*)d_in[17];
    const float* cWr      = (const float*)d_in[18];
    const float* cbr      = (const float*)d_in[19];
    const float* cWe      = (const float*)d_in[20];
    const float* catt     = (const float*)d_in[21];
    const float* cbias    = (const float*)d_in[22];
    const float* nW1      = (const float*)d_in[23];
    const float* nb1      = (const float*)d_in[24];
    const float* ng       = (const float*)d_in[25];
    const float* nbe      = (const float*)d_in[26];
    const float* nW2      = (const float*)d_in[27];
    const float* nb2      = (const float*)d_in[28];
    const float* pW1      = (const float*)d_in[29];
    const float* pb1      = (const float*)d_in[30];
    const float* pg       = (const float*)d_in[31];
    const float* pbe      = (const float*)d_in[32];
    const float* pW2      = (const float*)d_in[33];
    const float* pb2      = (const float*)d_in[34];
    const int* edge_index = (const int*)d_in[35];
    const int* batch      = (const int*)d_in[36];
    const int* ei_src = edge_index;
    const int* ei_dst = edge_index + N_EDGES;

    // workspace layout (base ~98.5 MB of f32; + ea if it fits: fp32 246 MB / fp16 123 MB)
    float* ws = (float*)d_ws;
    size_t off = 0;
    auto alloc = [&](size_t n) { float* p = ws + off; off += n; return p; };
    float* t_emb     = alloc((size_t)N_GRAPHS * HID);
    float* h         = alloc((size_t)N_NODES * HID);
    float* loop_attr = alloc((size_t)N_NODES * HID);
    float* cnt       = alloc((size_t)N_NODES);
    float* xl        = alloc((size_t)N_NODES * HID);
    float* xr        = alloc((size_t)N_NODES * HID);
    float* logit     = alloc((size_t)EF * HEADS);      // 4.08M floats
    float* mx        = alloc((size_t)N_NODES * HEADS);
    float* den       = alloc((size_t)N_NODES * HEADS);
    float* aggout    = alloc((size_t)N_NODES * HID);
    float* gsum      = alloc((size_t)N_GRAPHS * HID);
    float* gcnt      = alloc((size_t)N_GRAPHS);
    float* stat      = alloc((size_t)N_EDGES * 2);     // mean,rstd per edge (3.84 MB)
    size_t base_bytes = off * sizeof(float);
    float*  ea32 = ws + off;
    __half* ea16 = (__half*)(ws + off);
    int mode = 0;
    if (ws_size >= base_bytes + (size_t)N_EDGES * HID * sizeof(float)) mode = 2;
    else if (ws_size >= base_bytes + (size_t)N_EDGES * HID * sizeof(__half)) mode = 1;
    // aliases (disjoint lifetimes):
    float* xc   = logit;  // [N,72] = 2.16M floats, used only pre-layers; logit is 4.08M
    float* tmp1 = xl;     // used only post-layers
    (void)in_sizes; (void)n_in; (void)out_size;

    float* pred_noise = (float*)d_out;                              // [N,64]
    float* pred_props = (float*)d_out + (size_t)N_NODES * NODE_OUT; // [16,8]

    // 1. time MLP
    hipLaunchKernelGGL(time_mlp_kernel, dim3(N_GRAPHS), dim3(HID), 0, stream,
                       t, tW1, tb1, tW2, tb2, t_emb);
    // 2. concat
    hipLaunchKernelGGL(concat_kernel, dim3((N_NODES * 72 + 255) / 256), dim3(256), 0, stream,
                       x, conds, batch, xc);
    // 3. node encoder gemm + LN/GELU (+t_emb[batch])
    hipLaunchKernelGGL((gemm_kernel<HID, 8>), dim3(N_NODES / 8), dim3(HID), 0, stream,
                       xc, encW, encb, h, N_NODES, 72);
    hipLaunchKernelGGL(ln_gelu_kernel, dim3(N_NODES), dim3(HID), 0, stream,
                       h, encg, encbe, t_emb, batch);
    // 4. edge encode (stats always; ea memoized per mode) + self-loop segment-mean
    hipLaunchKernelGGL(zero_kernel, dim3(1024), dim3(256), 0, stream,
                       loop_attr, (long)N_NODES * HID);
    hipLaunchKernelGGL(zero_kernel, dim3(64), dim3(256), 0, stream, cnt, (long)N_NODES);
    if (mode == 2) {
        hipLaunchKernelGGL((edge_enc_loop_kernel<8, 2>), dim3(N_EDGES / 8), dim3(HID), 0, stream,
                           edge_attr, eW, eb, eg, ebe, ei_dst, loop_attr, cnt, stat, ea32, ea16);
    } else if (mode == 1) {
        hipLaunchKernelGGL((edge_enc_loop_kernel<8, 1>), dim3(N_EDGES / 8), dim3(HID), 0, stream,
                           edge_attr, eW, eb, eg, ebe, ei_dst, loop_attr, cnt, stat, ea32, ea16);
    } else {
        hipLaunchKernelGGL((edge_enc_loop_kernel<8, 0>), dim3(N_EDGES / 8), dim3(HID), 0, stream,
                           edge_attr, eW, eb, eg, ebe, ei_dst, loop_attr, cnt, stat, ea32, ea16);
    }
    hipLaunchKernelGGL(loop_div_kernel, dim3((N_NODES * HID + 255) / 256), dim3(256), 0, stream,
                       loop_attr, cnt);

    // 5. layers
    for (int l = 0; l < NLAYERS; ++l) {
        const float* cWl_l = cWl + (size_t)l * HID * HID;
        const float* cWr_l = cWr + (size_t)l * HID * HID;
        const float* cWe_l = cWe + (size_t)l * HID * HID;
        const float* cbl_l = cbl + (size_t)l * HID;
        const float* cbr_l = cbr + (size_t)l * HID;
        const float* catt_l = catt + (size_t)l * HID;
        const float* cbias_l = cbias + (size_t)l * HID;

        hipLaunchKernelGGL((gemm2_kernel<8>), dim3(N_NODES / 8), dim3(HID), 0, stream,
                           h, cWl_l, cbl_l, cWr_l, cbr_l, xl, xr, N_NODES);
        hipLaunchKernelGGL(init_mx_den_kernel, dim3((N_NODES * HEADS + 255) / 256), dim3(256), 0,
                           stream, mx, den);
        if (mode == 2) {
            hipLaunchKernelGGL((att_logit6_kernel<8>), dim3(EF / 8), dim3(HID), 0, stream,
                               ea32, loop_attr, cWe_l, catt_l, xl, xr, ei_src, ei_dst, logit, mx);
        } else if (mode == 1) {
            hipLaunchKernelGGL(att_logit8h_kernel, dim3(EF / 16), dim3(HID), 0, stream,
                               ea16, loop_attr, cWe_l, catt_l, xl, xr, ei_src, ei_dst, logit, mx);
        } else {
            hipLaunchKernelGGL((att_logit7_kernel<8>), dim3(EF / 8), dim3(HID), 0, stream,
                               edge_attr, eW, eb, eg, ebe, stat, loop_attr,
                               cWe_l, catt_l, xl, xr, ei_src, ei_dst, logit, mx);
        }
        hipLaunchKernelGGL(softmax_norm_kernel,
                           dim3((int)(((long)EF * HEADS + 255) / 256)), dim3(256), 0, stream,
                           ei_dst, mx, logit, den);
        hipLaunchKernelGGL(zero_kernel, dim3(1024), dim3(256), 0, stream,
                           aggout, (long)N_NODES * HID);
        hipLaunchKernelGGL(aggregate_kernel,
                           dim3((int)(((long)EF * HID + 255) / 256)), dim3(256), 0, stream,
                           logit, den, xl, ei_src, ei_dst, aggout);
        hipLaunchKernelGGL(residual_kernel, dim3((N_NODES * HID + 255) / 256), dim3(256), 0, stream,
                           aggout, cbias_l, h);
    }

    // 6. noise head
    hipLaunchKernelGGL((gemm_kernel<HID, 8>), dim3(N_NODES / 8), dim3(HID), 0, stream,
                       h, nW1, nb1, tmp1, N_NODES, HID);
    hipLaunchKernelGGL(ln_gelu_kernel, dim3(N_NODES), dim3(HID), 0, stream,
                       tmp1, ng, nbe, (const float*)nullptr, (const int*)nullptr);
    hipLaunchKernelGGL((gemm_kernel<NODE_OUT, 8>), dim3(N_NODES / 8), dim3(NODE_OUT), 0, stream,
                       tmp1, nW2, nb2, pred_noise, N_NODES, HID);

    // 7. pooling + props head
    hipLaunchKernelGGL(zero_kernel, dim3(4), dim3(256), 0, stream,
                       gsum, (long)N_GRAPHS * HID);
    hipLaunchKernelGGL(zero_kernel, dim3(1), dim3(64), 0, stream, gcnt, (long)N_GRAPHS);
    hipLaunchKernelGGL(pool_kernel, dim3((N_NODES + POOL_NODES - 1) / POOL_NODES), dim3(HID), 0,
                       stream, h, batch, gsum, gcnt);
    hipLaunchKernelGGL(props_kernel, dim3(N_GRAPHS), dim3(HID), 0, stream,
                       gsum, gcnt, pW1, pb1, pg, pbe, pW2, pb2, pred_props);
}

// Round 9
// 3218.675 us; speedup vs baseline: 1.9568x; 1.0125x over previous
//
#include <hip/hip_runtime.h>
#include <hip/hip_fp16.h>
#include <math.h>

#define N_NODES 30000
#define N_EDGES 480000
#define N_GRAPHS 16
#define HID 128
#define HEADS 8
#define HEAD_DIM 16
#define NODE_IN 64
#define EDGE_IN 32
#define COND 8
#define NODE_OUT 64
#define NLAYERS 4
#define EF (N_EDGES + N_NODES) /* 510000 */
#define LN_EPS 1e-5f

__device__ __forceinline__ float gelu_f(float x) {
    return 0.5f * x * (1.0f + erff(x * 0.70710678118654752440f));
}

__device__ __forceinline__ void atomicMaxF(float* addr, float val) {
    if (val >= 0.0f) {
        atomicMax((int*)addr, __float_as_int(val));
    } else {
        atomicMin((unsigned int*)addr, __float_as_uint(val));
    }
}

// ---------- generic zero ----------
__global__ void zero_kernel(float* __restrict__ p, long n) {
    long i = (long)blockIdx.x * blockDim.x + threadIdx.x;
    long stride = (long)gridDim.x * blockDim.x;
    for (; i < n; i += stride) p[i] = 0.0f;
}

// ---------- time MLP: t[16] -> t_emb[16,128] ----------
__global__ void time_mlp_kernel(const float* __restrict__ t,
                                const float* __restrict__ tW1, const float* __restrict__ tb1,
                                const float* __restrict__ tW2, const float* __restrict__ tb2,
                                float* __restrict__ t_emb) {
    __shared__ float hsh[HID];
    int b = blockIdx.x, j = threadIdx.x;
    float tv = t[b];
    hsh[j] = gelu_f(tv * tW1[j] + tb1[j]);
    __syncthreads();
    float acc = tb2[j];
    for (int k = 0; k < HID; ++k) acc += hsh[k] * tW2[k * HID + j];
    t_emb[b * HID + j] = acc;
}

// ---------- concat x(64) + conditions[batch](8) -> xc[N,72] ----------
__global__ void concat_kernel(const float* __restrict__ x, const float* __restrict__ cond,
                              const int* __restrict__ batch, float* __restrict__ xc) {
    int idx = blockIdx.x * blockDim.x + threadIdx.x;
    if (idx >= N_NODES * 72) return;
    int n = idx / 72, c = idx % 72;
    xc[idx] = (c < NODE_IN) ? x[n * NODE_IN + c] : cond[batch[n] * COND + (c - NODE_IN)];
}

// ---------- generic GEMM: C[M,NCOL] = A[M,K] @ B[K,NCOL] + bias ----------
template <int NCOL, int R>
__global__ void gemm_kernel(const float* __restrict__ A, const float* __restrict__ B,
                            const float* __restrict__ bias, float* __restrict__ C,
                            int M, int K) {
    __shared__ __align__(16) float sh[R * HID];
    int j = threadIdx.x;
    int row0 = blockIdx.x * R;
    int total = R * K;
    for (int i = j; i < total; i += NCOL) {
        int r = i / K, k = i - r * K;
        int row = row0 + r;
        sh[r * K + k] = (row < M) ? A[(long)row * K + k] : 0.0f;
    }
    __syncthreads();
    float acc[R];
    float bv = bias ? bias[j] : 0.0f;
#pragma unroll
    for (int r = 0; r < R; ++r) acc[r] = bv;
    int KB = K >> 2;
    for (int kb = 0; kb < KB; ++kb) {
        float w0 = B[(kb * 4 + 0) * NCOL + j];
        float w1 = B[(kb * 4 + 1) * NCOL + j];
        float w2 = B[(kb * 4 + 2) * NCOL + j];
        float w3 = B[(kb * 4 + 3) * NCOL + j];
#pragma unroll
        for (int r = 0; r < R; ++r) {
            float4 a = *(const float4*)&sh[r * K + kb * 4];
            acc[r] += a.x * w0 + a.y * w1 + a.z * w2 + a.w * w3;
        }
    }
#pragma unroll
    for (int r = 0; r < R; ++r) {
        int row = row0 + r;
        if (row < M) C[(long)row * NCOL + j] = acc[r];
    }
}

// ---------- fused dual GEMM: Cl = A@Bl + bl, Cr = A@Br + br (K = HID) ----------
template <int R>
__global__ void gemm2_kernel(const float* __restrict__ A,
                             const float* __restrict__ Bl, const float* __restrict__ bl,
                             const float* __restrict__ Br, const float* __restrict__ br,
                             float* __restrict__ Cl, float* __restrict__ Cr, int M) {
    __shared__ __align__(16) float sh[R * HID];
    int j = threadIdx.x;
    int row0 = blockIdx.x * R;
    for (int i = j; i < R * HID; i += HID) {
        int r = i >> 7, k = i & 127;
        int row = row0 + r;
        sh[i] = (row < M) ? A[(long)row * HID + k] : 0.0f;
    }
    __syncthreads();
    float accl[R], accr[R];
    float blv = bl[j], brv = br[j];
#pragma unroll
    for (int r = 0; r < R; ++r) { accl[r] = blv; accr[r] = brv; }
    for (int kb = 0; kb < HID / 4; ++kb) {
        float l0 = Bl[(kb * 4 + 0) * HID + j];
        float l1 = Bl[(kb * 4 + 1) * HID + j];
        float l2 = Bl[(kb * 4 + 2) * HID + j];
        float l3 = Bl[(kb * 4 + 3) * HID + j];
        float r0 = Br[(kb * 4 + 0) * HID + j];
        float r1 = Br[(kb * 4 + 1) * HID + j];
        float r2 = Br[(kb * 4 + 2) * HID + j];
        float r3 = Br[(kb * 4 + 3) * HID + j];
#pragma unroll
        for (int r = 0; r < R; ++r) {
            float4 a = *(const float4*)&sh[r * HID + kb * 4];
            accl[r] += a.x * l0 + a.y * l1 + a.z * l2 + a.w * l3;
            accr[r] += a.x * r0 + a.y * r1 + a.z * r2 + a.w * r3;
        }
    }
#pragma unroll
    for (int r = 0; r < R; ++r) {
        int row = row0 + r;
        if (row < M) {
            Cl[(long)row * HID + j] = accl[r];
            Cr[(long)row * HID + j] = accr[r];
        }
    }
}

// ---------- in-place LayerNorm + GELU (+ optional t_emb[batch[row]]) ----------
__global__ void ln_gelu_kernel(float* __restrict__ X, const float* __restrict__ g,
                               const float* __restrict__ bta,
                               const float* __restrict__ t_emb, const int* __restrict__ batch) {
    int row = blockIdx.x, j = threadIdx.x;
    __shared__ float red[HID];
    float v = X[(long)row * HID + j];
    red[j] = v;
    __syncthreads();
    for (int s = 64; s > 0; s >>= 1) { if (j < s) red[j] += red[j + s]; __syncthreads(); }
    float mean = red[0] * (1.0f / HID);
    __syncthreads();
    float d = v - mean;
    red[j] = d * d;
    __syncthreads();
    for (int s = 64; s > 0; s >>= 1) { if (j < s) red[j] += red[j + s]; __syncthreads(); }
    float var = red[0] * (1.0f / HID);
    float y = gelu_f(d * rsqrtf(var + LN_EPS) * g[j] + bta[j]);
    if (t_emb) y += t_emb[batch[row] * HID + j];
    X[(long)row * HID + j] = y;
}

// ---------- fallback (modes 0/2): edge-encode + segment-sum, LDS-tree LN ----------
template <int R, int MODE>
__global__ void edge_enc_loop_kernel(const float* __restrict__ edge_attr,
                                     const float* __restrict__ eW, const float* __restrict__ eb,
                                     const float* __restrict__ eg, const float* __restrict__ ebe,
                                     const int* __restrict__ ei_dst,
                                     float* __restrict__ loop_sum, float* __restrict__ cnt,
                                     float* __restrict__ stat,
                                     float* __restrict__ ea32, __half* __restrict__ ea16) {
    __shared__ float red[R * HID];
    __shared__ __align__(16) float sattr[R * EDGE_IN];
    __shared__ int sdst[R];
    int j = threadIdx.x;
    long e0 = (long)blockIdx.x * R;
    if (j < R * EDGE_IN / 4)
        ((float4*)sattr)[j] = ((const float4*)(edge_attr + e0 * EDGE_IN))[j];
    if (j < R) sdst[j] = ei_dst[e0 + j];
    __syncthreads();
    float val[R];
    float ebv = eb[j];
#pragma unroll
    for (int r = 0; r < R; ++r) val[r] = ebv;
#pragma unroll
    for (int kb = 0; kb < EDGE_IN / 4; ++kb) {
        float w0 = eW[(kb * 4 + 0) * HID + j];
        float w1 = eW[(kb * 4 + 1) * HID + j];
        float w2 = eW[(kb * 4 + 2) * HID + j];
        float w3 = eW[(kb * 4 + 3) * HID + j];
#pragma unroll
        for (int r = 0; r < R; ++r) {
            float4 a = *(const float4*)&sattr[r * EDGE_IN + kb * 4];
            val[r] += a.x * w0 + a.y * w1 + a.z * w2 + a.w * w3;
        }
    }
#pragma unroll
    for (int r = 0; r < R; ++r) red[r * HID + j] = val[r];
    __syncthreads();
    for (int s = 64; s > 0; s >>= 1) {
        if (j < s) {
#pragma unroll
            for (int r = 0; r < R; ++r) red[r * HID + j] += red[r * HID + j + s];
        }
        __syncthreads();
    }
    float mean[R];
#pragma unroll
    for (int r = 0; r < R; ++r) mean[r] = red[r * HID] * (1.0f / HID);
    __syncthreads();
#pragma unroll
    for (int r = 0; r < R; ++r) { float d = val[r] - mean[r]; red[r * HID + j] = d * d; }
    __syncthreads();
    for (int s = 64; s > 0; s >>= 1) {
        if (j < s) {
#pragma unroll
            for (int r = 0; r < R; ++r) red[r * HID + j] += red[r * HID + j + s];
        }
        __syncthreads();
    }
    float egv = eg[j], bev = ebe[j];
#pragma unroll
    for (int r = 0; r < R; ++r) {
        float var = red[r * HID] * (1.0f / HID);
        float rstd = rsqrtf(var + LN_EPS);
        float y = gelu_f((val[r] - mean[r]) * rstd * egv + bev);
        int d = sdst[r];
        long e = e0 + r;
        if (j == 0) { stat[e * 2] = mean[r]; stat[e * 2 + 1] = rstd; }
        if (MODE == 2) ea32[e * HID + j] = y;
        if (MODE == 1) ea16[e * HID + j] = __float2half(y);
        atomicAdd(&loop_sum[(long)d * HID + j], y);
        if (j == 0) atomicAdd(&cnt[d], 1.0f);
    }
}

// ---------- mode-1 MAIN enc: wave-owns-rows, shfl LN (no barriers), fp16 ea ----------
// 128 threads, 8 edges/block. Wave w rows w*4..w*4+3; lane holds cols (lane, lane+64).
__global__ __launch_bounds__(128) void edge_enc_loop_w_kernel(
        const float* __restrict__ edge_attr,
        const float* __restrict__ eW, const float* __restrict__ eb,
        const float* __restrict__ eg, const float* __restrict__ ebe,
        const int* __restrict__ ei_dst,
        float* __restrict__ loop_sum, float* __restrict__ cnt,
        __half* __restrict__ ea16) {
    const int R = 8;
    __shared__ __align__(16) float sattr[R * EDGE_IN];
    __shared__ int sdst[R];
    int t = threadIdx.x;
    long e0 = (long)blockIdx.x * R;
    if (t < R * EDGE_IN / 4)
        ((float4*)sattr)[t] = ((const float4*)(edge_attr + e0 * EDGE_IN))[t];
    if (t < R) sdst[t] = ei_dst[e0 + t];
    __syncthreads();
    int lane = t & 63, w = t >> 6;
    int r0 = w * 4;
    int j1 = lane, j2 = lane + 64;
    float eb1 = eb[j1], eb2 = eb[j2];
    float v0[4], v1[4];
#pragma unroll
    for (int q = 0; q < 4; ++q) { v0[q] = eb1; v1[q] = eb2; }
#pragma unroll
    for (int kb = 0; kb < EDGE_IN / 4; ++kb) {
        float w10 = eW[(kb * 4 + 0) * HID + j1];
        float w11 = eW[(kb * 4 + 1) * HID + j1];
        float w12 = eW[(kb * 4 + 2) * HID + j1];
        float w13 = eW[(kb * 4 + 3) * HID + j1];
        float w20 = eW[(kb * 4 + 0) * HID + j2];
        float w21 = eW[(kb * 4 + 1) * HID + j2];
        float w22 = eW[(kb * 4 + 2) * HID + j2];
        float w23 = eW[(kb * 4 + 3) * HID + j2];
#pragma unroll
        for (int q = 0; q < 4; ++q) {
            float4 a = *(const float4*)&sattr[(r0 + q) * EDGE_IN + kb * 4];
            v0[q] += a.x * w10 + a.y * w11 + a.z * w12 + a.w * w13;
            v1[q] += a.x * w20 + a.y * w21 + a.z * w22 + a.w * w23;
        }
    }
    float eg1 = eg[j1], eg2 = eg[j2];
    float be1 = ebe[j1], be2 = ebe[j2];
#pragma unroll
    for (int q = 0; q < 4; ++q) {
        float s1 = v0[q] + v1[q];
        float s2 = v0[q] * v0[q] + v1[q] * v1[q];
#pragma unroll
        for (int m = 1; m < 64; m <<= 1) {
            s1 += __shfl_xor(s1, m);
            s2 += __shfl_xor(s2, m);
        }
        float mean = s1 * (1.0f / 128.0f);
        float var = s2 * (1.0f / 128.0f) - mean * mean;
        float rstd = rsqrtf(var + LN_EPS);
        float y0 = gelu_f((v0[q] - mean) * rstd * eg1 + be1);
        float y1 = gelu_f((v1[q] - mean) * rstd * eg2 + be2);
        long e = e0 + r0 + q;
        int d = sdst[r0 + q];
        ea16[e * HID + j1] = __float2half(y0);
        ea16[e * HID + j2] = __float2half(y1);
        atomicAdd(&loop_sum[(long)d * HID + j1], y0);
        atomicAdd(&loop_sum[(long)d * HID + j2], y1);
        if (lane == 0) atomicAdd(&cnt[d], 1.0f);
    }
}

__global__ void loop_div_kernel(float* __restrict__ loop_attr, const float* __restrict__ cnt) {
    int idx = blockIdx.x * blockDim.x + threadIdx.x;
    if (idx >= N_NODES * HID) return;
    int n = idx >> 7;
    loop_attr[idx] = loop_attr[idx] / fmaxf(cnt[n], 1.0f);
}

// ---------- init mx=-inf, den=0 ----------
__global__ void init_mx_den_kernel(float* __restrict__ mx, float* __restrict__ den) {
    int idx = blockIdx.x * blockDim.x + threadIdx.x;
    if (idx >= N_NODES * HEADS) return;
    mx[idx] = -INFINITY;
    den[idx] = 0.0f;
}

// ---------- shared epilogue (1 col/thread fallback variants) ----------
template <int R>
__device__ __forceinline__ void em_logit_body(
        const float* __restrict__ sh, const int* __restrict__ ssrc, const int* __restrict__ sdst,
        const float* __restrict__ cWe_l, const float* __restrict__ catt_l,
        const float* __restrict__ xl, const float* __restrict__ xr,
        float* __restrict__ logit, float* __restrict__ mx, long e0, int j) {
    float acc[R];
#pragma unroll
    for (int r = 0; r < R; ++r) acc[r] = 0.0f;
    for (int kb = 0; kb < HID / 4; ++kb) {
        float w0 = cWe_l[(kb * 4 + 0) * HID + j];
        float w1 = cWe_l[(kb * 4 + 1) * HID + j];
        float w2 = cWe_l[(kb * 4 + 2) * HID + j];
        float w3 = cWe_l[(kb * 4 + 3) * HID + j];
#pragma unroll
        for (int r = 0; r < R; ++r) {
            float4 a = *(const float4*)&sh[r * HID + kb * 4];
            acc[r] += a.x * w0 + a.y * w1 + a.z * w2 + a.w * w3;
        }
    }
    float cj = catt_l[j];
    int head = j >> 4;
#pragma unroll
    for (int r = 0; r < R; ++r) {
        long e = e0 + r;
        int s = ssrc[r], d = sdst[r];
        float m = xl[(long)s * HID + j] + xr[(long)d * HID + j] + acc[r];
        m = (m > 0.0f) ? m : 0.2f * m;
        float p = m * cj;
        p += __shfl_down(p, 8, 16);
        p += __shfl_down(p, 4, 16);
        p += __shfl_down(p, 2, 16);
        p += __shfl_down(p, 1, 16);
        if ((j & 15) == 0) {
            logit[e * HEADS + head] = p;
            atomicMaxF(&mx[(long)d * HEADS + head], p);
        }
    }
}

// ---------- att kernel, mode 0 fallback: re-encode with CACHED LN stats ----------
template <int R>
__global__ void att_logit7_kernel(const float* __restrict__ edge_attr,
                                  const float* __restrict__ eW, const float* __restrict__ eb,
                                  const float* __restrict__ eg, const float* __restrict__ ebe,
                                  const float* __restrict__ stat,
                                  const float* __restrict__ loop_attr,
                                  const float* __restrict__ cWe_l, const float* __restrict__ catt_l,
                                  const float* __restrict__ xl, const float* __restrict__ xr,
                                  const int* __restrict__ ei_src, const int* __restrict__ ei_dst,
                                  float* __restrict__ logit, float* __restrict__ mx) {
    __shared__ __align__(16) float sh[R * HID];
    __shared__ __align__(16) float sattr[R * EDGE_IN];
    __shared__ float sstat[R * 2];
    __shared__ int ssrc[R], sdst[R];
    int j = threadIdx.x;
    long e0 = (long)blockIdx.x * R;
    bool realblk = (e0 < N_EDGES);

    if (realblk) {
        if (j < R * EDGE_IN / 4)
            ((float4*)sattr)[j] = ((const float4*)(edge_attr + e0 * EDGE_IN))[j];
        if (j < R * 2) sstat[j] = stat[e0 * 2 + j];
        if (j < R) { ssrc[j] = ei_src[e0 + j]; sdst[j] = ei_dst[e0 + j]; }
    } else {
        if (j < R) ssrc[j] = sdst[j] = (int)(e0 + j - N_EDGES);
    }
    __syncthreads();

    if (realblk) {
        float val[R];
        float ebv = eb[j];
#pragma unroll
        for (int r = 0; r < R; ++r) val[r] = ebv;
#pragma unroll
        for (int kb = 0; kb < EDGE_IN / 4; ++kb) {
            float w0 = eW[(kb * 4 + 0) * HID + j];
            float w1 = eW[(kb * 4 + 1) * HID + j];
            float w2 = eW[(kb * 4 + 2) * HID + j];
            float w3 = eW[(kb * 4 + 3) * HID + j];
#pragma unroll
            for (int r = 0; r < R; ++r) {
                float4 a = *(const float4*)&sattr[r * EDGE_IN + kb * 4];
                val[r] += a.x * w0 + a.y * w1 + a.z * w2 + a.w * w3;
            }
        }
        float egv = eg[j], bev = ebe[j];
#pragma unroll
        for (int r = 0; r < R; ++r) {
            float mean = sstat[r * 2], rstd = sstat[r * 2 + 1];
            sh[r * HID + j] = gelu_f((val[r] - mean) * rstd * egv + bev);
        }
    } else {
#pragma unroll
        for (int r = 0; r < R; ++r)
            sh[r * HID + j] = loop_attr[(long)(e0 + r - N_EDGES) * HID + j];
    }
    __syncthreads();
    em_logit_body<R>(sh, ssrc, sdst, cWe_l, catt_l, xl, xr, logit, mx, e0, j);
}

// ---------- att kernel, mode 2 fallback: stream fp32 ea ----------
template <int R>
__global__ void att_logit6_kernel(const float* __restrict__ ea,
                                  const float* __restrict__ loop_attr,
                                  const float* __restrict__ cWe_l, const float* __restrict__ catt_l,
                                  const float* __restrict__ xl, const float* __restrict__ xr,
                                  const int* __restrict__ ei_src, const int* __restrict__ ei_dst,
                                  float* __restrict__ logit, float* __restrict__ mx) {
    __shared__ __align__(16) float sh[R * HID];
    __shared__ int ssrc[R], sdst[R];
    int j = threadIdx.x;
    long e0 = (long)blockIdx.x * R;
    bool realblk = (e0 < N_EDGES);
    const float* srcp = realblk ? (ea + e0 * HID) : (loop_attr + (e0 - N_EDGES) * HID);
    const float4* s4 = (const float4*)srcp;
    ((float4*)sh)[j]       = s4[j];
    ((float4*)sh)[j + HID] = s4[j + HID];
    if (j < R) {
        long e = e0 + j;
        if (realblk) { ssrc[j] = ei_src[e]; sdst[j] = ei_dst[e]; }
        else         { ssrc[j] = sdst[j] = (int)(e - N_EDGES); }
    }
    __syncthreads();
    em_logit_body<R>(sh, ssrc, sdst, cWe_l, catt_l, xl, xr, logit, mx, e0, j);
}

// ---------- att kernel, mode 1 MAIN: fp16 ea stream, 16-edge tile, 4 cols/thread ----------
// Thread: cg=t&31 -> cols cg*4..cg*4+3 (float4 weight loads); rg=t>>5 -> rows rg*4..rg*4+3.
// Per kb: 4 broadcast ds_read_b128 + 4 coalesced float4 weight loads feed 64 FMA.
__global__ __launch_bounds__(128) void att_logit9h_kernel(
        const __half* __restrict__ ea,
        const float* __restrict__ loop_attr,
        const float* __restrict__ cWe_l, const float* __restrict__ catt_l,
        const float* __restrict__ xl, const float* __restrict__ xr,
        const int* __restrict__ ei_src, const int* __restrict__ ei_dst,
        float* __restrict__ logit, float* __restrict__ mx) {
    const int R = 16;
    __shared__ __align__(16) float sh[R * HID];
    __shared__ int ssrc[R], sdst[R];
    int t = threadIdx.x;
    long e0 = (long)blockIdx.x * R;
    bool realblk = (e0 < N_EDGES);

    // stage 16 rows into LDS
    if (realblk) {
        const uint4* s16 = (const uint4*)(ea + e0 * HID);  // 256 uint4 of fp16
#pragma unroll
        for (int i = 0; i < 2; ++i) {
            uint4 u = s16[t + i * 128];
            int base = (t + i * 128) * 8;
            const __half2* hp = (const __half2*)&u;
            float2 f0 = __half22float2(hp[0]);
            float2 f1 = __half22float2(hp[1]);
            float2 f2 = __half22float2(hp[2]);
            float2 f3 = __half22float2(hp[3]);
            *(float4*)&sh[base]     = make_float4(f0.x, f0.y, f1.x, f1.y);
            *(float4*)&sh[base + 4] = make_float4(f2.x, f2.y, f3.x, f3.y);
        }
    } else {
        const float4* s4 = (const float4*)(loop_attr + (e0 - N_EDGES) * HID);
#pragma unroll
        for (int i = 0; i < 4; ++i)
            ((float4*)sh)[t + i * 128] = s4[t + i * 128];
    }
    if (t < R) {
        long e = e0 + t;
        if (realblk) { ssrc[t] = ei_src[e]; sdst[t] = ei_dst[e]; }
        else         { ssrc[t] = sdst[t] = (int)(e - N_EDGES); }
    }
    __syncthreads();

    int cg = t & 31, rg = t >> 5;
    int c0 = cg * 4;
    float acc[4][4];
#pragma unroll
    for (int i = 0; i < 4; ++i)
#pragma unroll
        for (int c = 0; c < 4; ++c) acc[i][c] = 0.0f;
    for (int kb = 0; kb < HID / 4; ++kb) {
        float4 w0 = *(const float4*)&cWe_l[(kb * 4 + 0) * HID + c0];
        float4 w1 = *(const float4*)&cWe_l[(kb * 4 + 1) * HID + c0];
        float4 w2 = *(const float4*)&cWe_l[(kb * 4 + 2) * HID + c0];
        float4 w3 = *(const float4*)&cWe_l[(kb * 4 + 3) * HID + c0];
#pragma unroll
        for (int i = 0; i < 4; ++i) {
            float4 a = *(const float4*)&sh[(rg * 4 + i) * HID + kb * 4];
            acc[i][0] += a.x * w0.x + a.y * w1.x + a.z * w2.x + a.w * w3.x;
            acc[i][1] += a.x * w0.y + a.y * w1.y + a.z * w2.y + a.w * w3.y;
            acc[i][2] += a.x * w0.z + a.y * w1.z + a.z * w2.z + a.w * w3.z;
            acc[i][3] += a.x * w0.w + a.y * w1.w + a.z * w2.w + a.w * w3.w;
        }
    }

    float4 cat4 = *(const float4*)&catt_l[c0];
    int head = cg >> 2;
#pragma unroll
    for (int i = 0; i < 4; ++i) {
        int r = rg * 4 + i;
        long e = e0 + r;
        int s = ssrc[r], d = sdst[r];
        float4 xlv = *(const float4*)&xl[(long)s * HID + c0];
        float4 xrv = *(const float4*)&xr[(long)d * HID + c0];
        float m0 = xlv.x + xrv.x + acc[i][0]; m0 = (m0 > 0.0f) ? m0 : 0.2f * m0;
        float m1 = xlv.y + xrv.y + acc[i][1]; m1 = (m1 > 0.0f) ? m1 : 0.2f * m1;
        float m2 = xlv.z + xrv.z + acc[i][2]; m2 = (m2 > 0.0f) ? m2 : 0.2f * m2;
        float m3 = xlv.w + xrv.w + acc[i][3]; m3 = (m3 > 0.0f) ? m3 : 0.2f * m3;
        float p = m0 * cat4.x + m1 * cat4.y + m2 * cat4.z + m3 * cat4.w;
        p += __shfl_xor(p, 1);
        p += __shfl_xor(p, 2);
        if ((cg & 3) == 0) {
            logit[e * HEADS + head] = p;
            atomicMaxF(&mx[(long)d * HEADS + head], p);
        }
    }
}

// ---------- exp(logit-mx), accumulate denominator ----------
__global__ void softmax_norm_kernel(const int* __restrict__ ei_dst, const float* __restrict__ mx,
                                    float* __restrict__ logit, float* __restrict__ den) {
    long idx = (long)blockIdx.x * blockDim.x + threadIdx.x;
    if (idx >= (long)EF * HEADS) return;
    long e = idx >> 3;
    int hh = (int)(idx & 7);
    int d = (e < N_EDGES) ? ei_dst[e] : (int)(e - N_EDGES);
    float ex = expf(logit[idx] - mx[(long)d * HEADS + hh]);
    logit[idx] = ex;
    atomicAdd(&den[(long)d * HEADS + hh], ex);
}

// ---------- alpha-weighted aggregation ----------
__global__ void aggregate_kernel(const float* __restrict__ logit, const float* __restrict__ den,
                                 const float* __restrict__ xl,
                                 const int* __restrict__ ei_src, const int* __restrict__ ei_dst,
                                 float* __restrict__ aggout) {
    long idx = (long)blockIdx.x * blockDim.x + threadIdx.x;
    if (idx >= (long)EF * HID) return;
    long e = idx >> 7;
    int j = (int)(idx & 127);
    int s, d;
    if (e < N_EDGES) { s = ei_src[e]; d = ei_dst[e]; }
    else             { s = d = (int)(e - N_EDGES); }
    int head = j >> 4;
    float alpha = logit[e * HEADS + head] / (den[(long)d * HEADS + head] + 1e-16f);
    atomicAdd(&aggout[(long)d * HID + j], alpha * xl[(long)s * HID + j]);
}

// ---------- h = gelu(aggout + cbias) + h ----------
__global__ void residual_kernel(const float* __restrict__ aggout, const float* __restrict__ cbias_l,
                                float* __restrict__ h) {
    int idx = blockIdx.x * blockDim.x + threadIdx.x;
    if (idx >= N_NODES * HID) return;
    int j = idx & 127;
    h[idx] = gelu_f(aggout[idx] + cbias_l[j]) + h[idx];
}

// ---------- pooling ----------
#define POOL_NODES 64
__global__ void pool_kernel(const float* __restrict__ h, const int* __restrict__ batch,
                            float* __restrict__ gsum, float* __restrict__ gcnt) {
    __shared__ float acc[N_GRAPHS][HID];
    __shared__ float cnt_sh[N_GRAPHS];
    int j = threadIdx.x;
    for (int g = 0; g < N_GRAPHS; ++g) acc[g][j] = 0.0f;
    if (j < N_GRAPHS) cnt_sh[j] = 0.0f;
    __syncthreads();
    int n0 = blockIdx.x * POOL_NODES;
    for (int i = 0; i < POOL_NODES; ++i) {
        int n = n0 + i;
        if (n >= N_NODES) break;
        int g = batch[n];
        acc[g][j] += h[(long)n * HID + j];
        if (j == 0) cnt_sh[g] += 1.0f;
    }
    __syncthreads();
    for (int g = 0; g < N_GRAPHS; ++g) atomicAdd(&gsum[g * HID + j], acc[g][j]);
    if (j < N_GRAPHS) atomicAdd(&gcnt[j], cnt_sh[j]);
}

// ---------- props head ----------
__global__ void props_kernel(const float* __restrict__ gsum, const float* __restrict__ gcnt,
                             const float* __restrict__ pW1, const float* __restrict__ pb1,
                             const float* __restrict__ pg, const float* __restrict__ pbe,
                             const float* __restrict__ pW2, const float* __restrict__ pb2,
                             float* __restrict__ out_props) {
    int g = blockIdx.x, j = threadIdx.x;
    __shared__ float feat[HID], red[HID], t2[HID];
    float c = fmaxf(gcnt[g], 1.0f);
    feat[j] = gsum[g * HID + j] / c;
    __syncthreads();
    float acc = pb1[j];
    for (int k = 0; k < HID; ++k) acc += feat[k] * pW1[k * HID + j];
    red[j] = acc;
    __syncthreads();
    for (int s = 64; s > 0; s >>= 1) { if (j < s) red[j] += red[j + s]; __syncthreads(); }
    float mean = red[0] * (1.0f / HID);
    __syncthreads();
    float dd = acc - mean;
    red[j] = dd * dd;
    __syncthreads();
    for (int s = 64; s > 0; s >>= 1) { if (j < s) red[j] += red[j + s]; __syncthreads(); }
    float var = red[0] * (1.0f / HID);
    t2[j] = gelu_f(dd * rsqrtf(var + LN_EPS) * pg[j] + pbe[j]);
    __syncthreads();
    if (j < COND) {
        float a = pb2[j];
        for (int k = 0; k < HID; ++k) a += t2[k] * pW2[k * COND + j];
        out_props[g * COND + j] = a;
    }
}

extern "C" void kernel_launch(void* const* d_in, const int* in_sizes, int n_in,
                              void* d_out, int out_size, void* d_ws, size_t ws_size,
                              hipStream_t stream) {
    const float* x        = (const float*)d_in[0];
    const float* edge_attr= (const float*)d_in[1];
    const float* t        = (const float*)d_in[2];
    const float* conds    = (const float*)d_in[3];
    const float* tW1      = (const float*)d_in[4];
    const float* tb1      = (const float*)d_in[5];
    const float* tW2      = (const float*)d_in[6];
    const float* tb2      = (const float*)d_in[7];
    const float* encW     = (const float*)d_in[8];
    const float* encb     = (const float*)d_in[9];
    const float* encg     = (const float*)d_in[10];
    const float* encbe    = (const float*)d_in[11];
    const float* eW       = (const float*)d_in[12];
    const float* eb       = (const float*)d_in[13];
    const float* eg       = (const float*)d_in[14];
    const float* ebe      = (const float*)d_in[15];
    const float* cWl      = (const float*)d_in[16];
    const float* cbl      = (const float*)d_in[17];
    const float* cWr      = (const float*)d_in[18];
    const float* cbr      = (const float*)d_in[19];
    const float* cWe      = (const float*)d_in[20];
    const float* catt     = (const float*)d_in[21];
    const float* cbias    = (const float*)d_in[22];
    const float* nW1      = (const float*)d_in[23];
    const float* nb1      = (const float*)d_in[24];
    const float* ng       = (const float*)d_in[25];
    const float* nbe      = (const float*)d_in[26];
    const float* nW2      = (const float*)d_in[27];
    const float* nb2      = (const float*)d_in[28];
    const float* pW1      = (const float*)d_in[29];
    const float* pb1      = (const float*)d_in[30];
    const float* pg       = (const float*)d_in[31];
    const float* pbe      = (const float*)d_in[32];
    const float* pW2      = (const float*)d_in[33];
    const float* pb2      = (const float*)d_in[34];
    const int* edge_index = (const int*)d_in[35];
    const int* batch      = (const int*)d_in[36];
    const int* ei_src = edge_index;
    const int* ei_dst = edge_index + N_EDGES;

    // workspace layout (base ~98.5 MB of f32; + ea if it fits: fp32 246 MB / fp16 123 MB)
    float* ws = (float*)d_ws;
    size_t off = 0;
    auto alloc = [&](size_t n) { float* p = ws + off; off += n; return p; };
    float* t_emb     = alloc((size_t)N_GRAPHS * HID);
    float* h         = alloc((size_t)N_NODES * HID);
    float* loop_attr = alloc((size_t)N_NODES * HID);
    float* cnt       = alloc((size_t)N_NODES);
    float* xl        = alloc((size_t)N_NODES * HID);
    float* xr        = alloc((size_t)N_NODES * HID);
    float* logit     = alloc((size_t)EF * HEADS);      // 4.08M floats
    float* mx        = alloc((size_t)N_NODES * HEADS);
    float* den       = alloc((size_t)N_NODES * HEADS);
    float* aggout    = alloc((size_t)N_NODES * HID);
    float* gsum      = alloc((size_t)N_GRAPHS * HID);
    float* gcnt      = alloc((size_t)N_GRAPHS);
    float* stat      = alloc((size_t)N_EDGES * 2);     // mean,rstd per edge (3.84 MB)
    size_t base_bytes = off * sizeof(float);
    float*  ea32 = ws + off;
    __half* ea16 = (__half*)(ws + off);
    int mode = 0;
    if (ws_size >= base_bytes + (size_t)N_EDGES * HID * sizeof(float)) mode = 2;
    else if (ws_size >= base_bytes + (size_t)N_EDGES * HID * sizeof(__half)) mode = 1;
    // aliases (disjoint lifetimes):
    float* xc   = logit;  // [N,72] = 2.16M floats, used only pre-layers; logit is 4.08M
    float* tmp1 = xl;     // used only post-layers
    (void)in_sizes; (void)n_in; (void)out_size;

    float* pred_noise = (float*)d_out;                              // [N,64]
    float* pred_props = (float*)d_out + (size_t)N_NODES * NODE_OUT; // [16,8]

    // 1. time MLP
    hipLaunchKernelGGL(time_mlp_kernel, dim3(N_GRAPHS), dim3(HID), 0, stream,
                       t, tW1, tb1, tW2, tb2, t_emb);
    // 2. concat
    hipLaunchKernelGGL(concat_kernel, dim3((N_NODES * 72 + 255) / 256), dim3(256), 0, stream,
                       x, conds, batch, xc);
    // 3. node encoder gemm + LN/GELU (+t_emb[batch])
    hipLaunchKernelGGL((gemm_kernel<HID, 8>), dim3(N_NODES / 8), dim3(HID), 0, stream,
                       xc, encW, encb, h, N_NODES, 72);
    hipLaunchKernelGGL(ln_gelu_kernel, dim3(N_NODES), dim3(HID), 0, stream,
                       h, encg, encbe, t_emb, batch);
    // 4. edge encode (ea memoized per mode) + self-loop segment-mean
    hipLaunchKernelGGL(zero_kernel, dim3(1024), dim3(256), 0, stream,
                       loop_attr, (long)N_NODES * HID);
    hipLaunchKernelGGL(zero_kernel, dim3(64), dim3(256), 0, stream, cnt, (long)N_NODES);
    if (mode == 2) {
        hipLaunchKernelGGL((edge_enc_loop_kernel<8, 2>), dim3(N_EDGES / 8), dim3(HID), 0, stream,
                           edge_attr, eW, eb, eg, ebe, ei_dst, loop_attr, cnt, stat, ea32, ea16);
    } else if (mode == 1) {
        hipLaunchKernelGGL(edge_enc_loop_w_kernel, dim3(N_EDGES / 8), dim3(128), 0, stream,
                           edge_attr, eW, eb, eg, ebe, ei_dst, loop_attr, cnt, ea16);
    } else {
        hipLaunchKernelGGL((edge_enc_loop_kernel<8, 0>), dim3(N_EDGES / 8), dim3(HID), 0, stream,
                           edge_attr, eW, eb, eg, ebe, ei_dst, loop_attr, cnt, stat, ea32, ea16);
    }
    hipLaunchKernelGGL(loop_div_kernel, dim3((N_NODES * HID + 255) / 256), dim3(256), 0, stream,
                       loop_attr, cnt);

    // 5. layers
    for (int l = 0; l < NLAYERS; ++l) {
        const float* cWl_l = cWl + (size_t)l * HID * HID;
        const float* cWr_l = cWr + (size_t)l * HID * HID;
        const float* cWe_l = cWe + (size_t)l * HID * HID;
        const float* cbl_l = cbl + (size_t)l * HID;
        const float* cbr_l = cbr + (size_t)l * HID;
        const float* catt_l = catt + (size_t)l * HID;
        const float* cbias_l = cbias + (size_t)l * HID;

        hipLaunchKernelGGL((gemm2_kernel<8>), dim3(N_NODES / 8), dim3(HID), 0, stream,
                           h, cWl_l, cbl_l, cWr_l, cbr_l, xl, xr, N_NODES);
        hipLaunchKernelGGL(init_mx_den_kernel, dim3((N_NODES * HEADS + 255) / 256), dim3(256), 0,
                           stream, mx, den);
        if (mode == 2) {
            hipLaunchKernelGGL((att_logit6_kernel<8>), dim3(EF / 8), dim3(HID), 0, stream,
                               ea32, loop_attr, cWe_l, catt_l, xl, xr, ei_src, ei_dst, logit, mx);
        } else if (mode == 1) {
            hipLaunchKernelGGL(att_logit9h_kernel, dim3(EF / 16), dim3(128), 0, stream,
                               ea16, loop_attr, cWe_l, catt_l, xl, xr, ei_src, ei_dst, logit, mx);
        } else {
            hipLaunchKernelGGL((att_logit7_kernel<8>), dim3(EF / 8), dim3(HID), 0, stream,
                               edge_attr, eW, eb, eg, ebe, stat, loop_attr,
                               cWe_l, catt_l, xl, xr, ei_src, ei_dst, logit, mx);
        }
        hipLaunchKernelGGL(softmax_norm_kernel,
                           dim3((int)(((long)EF * HEADS + 255) / 256)), dim3(256), 0, stream,
                           ei_dst, mx, logit, den);
        hipLaunchKernelGGL(zero_kernel, dim3(1024), dim3(256), 0, stream,
                           aggout, (long)N_NODES * HID);
        hipLaunchKernelGGL(aggregate_kernel,
                           dim3((int)(((long)EF * HID + 255) / 256)), dim3(256), 0, stream,
                           logit, den, xl, ei_src, ei_dst, aggout);
        hipLaunchKernelGGL(residual_kernel, dim3((N_NODES * HID + 255) / 256), dim3(256), 0, stream,
                           aggout, cbias_l, h);
    }

    // 6. noise head
    hipLaunchKernelGGL((gemm_kernel<HID, 8>), dim3(N_NODES / 8), dim3(HID), 0, stream,
                       h, nW1, nb1, tmp1, N_NODES, HID);
    hipLaunchKernelGGL(ln_gelu_kernel, dim3(N_NODES), dim3(HID), 0, stream,
                       tmp1, ng, nbe, (const float*)nullptr, (const int*)nullptr);
    hipLaunchKernelGGL((gemm_kernel<NODE_OUT, 8>), dim3(N_NODES / 8), dim3(NODE_OUT), 0, stream,
                       tmp1, nW2, nb2, pred_noise, N_NODES, HID);

    // 7. pooling + props head
    hipLaunchKernelGGL(zero_kernel, dim3(4), dim3(256), 0, stream,
                       gsum, (long)N_GRAPHS * HID);
    hipLaunchKernelGGL(zero_kernel, dim3(1), dim3(64), 0, stream, gcnt, (long)N_GRAPHS);
    hipLaunchKernelGGL(pool_kernel, dim3((N_NODES + POOL_NODES - 1) / POOL_NODES), dim3(HID), 0,
                       stream, h, batch, gsum, gcnt);
    hipLaunchKernelGGL(props_kernel, dim3(N_GRAPHS), dim3(HID), 0, stream,
                       gsum, gcnt, pW1, pb1, pg, pbe, pW2, pb2, pred_props);
}